// Round 9
// baseline (362.401 us; speedup 1.0000x reference)
//
#include <hip/hip_runtime.h>
#include <hip/hip_fp16.h>

#define NCH 64
#define EPS 1e-5f
#define SBANKS 32   // stats atomic banks
#define BSHIFT 8    // 256 dst nodes per bucket
#define NHIST 1024  // blocks in hist/bin passes (4 blocks/CU -> latency hiding)
#define SRCMASK 0x1FFFFu
#define QW_SCALE 32767.0f
#define QW_INV (1.0f/32767.0f)

typedef _Float16 f16x8 __attribute__((ext_vector_type(8)));
typedef float f32x4 __attribute__((ext_vector_type(4)));

// ---------------- fused front: x cast + W1/W2 pack + bucket histogram ----------------
__global__ __launch_bounds__(256) void k_front(const float* __restrict__ x, __half* __restrict__ xh,
                                               int castTotal, int castB,
                                               const float* __restrict__ W1, _Float16* __restrict__ Wb1,
                                               const float* __restrict__ W2, _Float16* __restrict__ Wb2,
                                               const int* __restrict__ dst, int* __restrict__ cnt,
                                               int E, int per, int nbuck) {
    int bid = blockIdx.x;
    if (bid < castB) {
        int i = (bid * 256 + threadIdx.x) * 4;
        if (i < castTotal) {
            float4 f = *(const float4*)(x + i);
            __half2* o = (__half2*)(xh + i);
            o[0] = __floats2half2_rn(f.x, f.y);
            o[1] = __floats2half2_rn(f.z, f.w);
        }
        return;
    }
    if (bid < castB + 96) {
        // W pack: Wb[((tile*6+kk)*64+lane)*8+j] = W[kk*32+(lane>>4)*8+j][tile*16+(lane&15)]
        int wb = bid - castB;
        const float* W = (wb < 48) ? W1 : W2;
        _Float16* Wb = (wb < 48) ? Wb1 : Wb2;
        int idx = (wb % 48) * 256 + threadIdx.x;   // 0..12287
        int j = idx & 7;
        int lane = (idx >> 3) & 63;
        int tk = idx >> 9;
        int tile = tk / 6, kk = tk % 6;
        int k = kk * 32 + (lane >> 4) * 8 + j;
        int n = tile * 16 + (lane & 15);
        Wb[idx] = (_Float16)W[k * 64 + n];
        return;
    }
    // histogram role
    __shared__ int lh[512];
    int hb = bid - castB - 96;
    for (int t = threadIdx.x; t < nbuck; t += 256) lh[t] = 0;
    __syncthreads();
    int lo = hb * per, hi = min(E, lo + per);
    for (int e = lo + threadIdx.x; e < hi; e += 256)
        atomicAdd(&lh[dst[e] >> BSHIFT], 1);
    __syncthreads();
    for (int t = threadIdx.x; t < nbuck; t += 256)
        if (lh[t]) atomicAdd(&cnt[t], lh[t]);
}

// ---------------- scan bucket counts -> base & cursor ----------------
__global__ void k_bscan(const int* __restrict__ cnt, int* __restrict__ gbase,
                        int* __restrict__ gcur, int nbuck, int E) {
    __shared__ int s[512];
    int t = threadIdx.x;
    int v = (t < nbuck) ? cnt[t] : 0;
    s[t] = v;
    __syncthreads();
    for (int off = 1; off < 512; off <<= 1) {
        int add = (t >= off) ? s[t - off] : 0;
        __syncthreads();
        s[t] += add;
        __syncthreads();
    }
    if (t < nbuck) { int ex = s[t] - v; gbase[t] = ex; gcur[t] = ex; }
    if (t == 0) gbase[nbuck] = E;
}

// ---------------- bin edges into bucket segments ----------------
__global__ __launch_bounds__(256) void k_bin(const int* __restrict__ src,
                                             const int* __restrict__ dst,
                                             int* __restrict__ gcur,
                                             int2* __restrict__ binned, int E, int per, int nbuck) {
    __shared__ int lh[512];
    __shared__ int lcur[512];
    for (int t = threadIdx.x; t < nbuck; t += 256) lh[t] = 0;
    __syncthreads();
    int lo = blockIdx.x * per, hi = min(E, lo + per);
    for (int e = lo + threadIdx.x; e < hi; e += 256)
        atomicAdd(&lh[dst[e] >> BSHIFT], 1);
    __syncthreads();
    for (int t = threadIdx.x; t < nbuck; t += 256) {
        int c = lh[t];
        lcur[t] = c ? atomicAdd(&gcur[t], c) : 0;
    }
    __syncthreads();
    for (int e = lo + threadIdx.x; e < hi; e += 256) {
        int d = dst[e];
        int b = d >> BSHIFT;
        int pos = atomicAdd(&lcur[b], 1);
        binned[pos] = make_int2(src[e], d);
    }
}

// ---------------- per-bucket CSR build: entry = src(17b) | deg_d(15b) ----------------
__global__ __launch_bounds__(256) void k_bucket(const int2* __restrict__ binned,
                                                const int* __restrict__ gbase,
                                                float* __restrict__ dinv,
                                                int* __restrict__ rowstart,
                                                unsigned int* __restrict__ csr, int N, int nbuck, int E) {
    __shared__ int hist[256];
    __shared__ int lcur[256];
    __shared__ int ltmp[256];
    int b = blockIdx.x;
    int t = threadIdx.x;
    int nodeLo = b << BSHIFT;
    int nHere = min(256, N - nodeLo);
    int e0 = gbase[b], e1 = gbase[b + 1];
    hist[t] = 0;
    __syncthreads();
    for (int e = e0 + t; e < e1; e += 256)
        atomicAdd(&hist[binned[e].y - nodeLo], 1);
    __syncthreads();
    int deg = (t < nHere) ? hist[t] : 0;
    if (t < nHere) dinv[nodeLo + t] = (deg > 0) ? rsqrtf((float)deg) : 0.0f;
    ltmp[t] = deg;
    __syncthreads();
    for (int off = 1; off < 256; off <<= 1) {
        int add = (t >= off) ? ltmp[t - off] : 0;
        __syncthreads();
        ltmp[t] += add;
        __syncthreads();
    }
    int lstart = ltmp[t] - deg;
    if (t < nHere) rowstart[nodeLo + t] = e0 + lstart;
    if (b == nbuck - 1 && t == 0) rowstart[N] = E;
    lcur[t] = lstart;
    __syncthreads();
    for (int e = e0 + t; e < e1; e += 256) {
        int2 sd = binned[e];
        int dl = sd.y - nodeLo;
        int pos = atomicAdd(&lcur[dl], 1);
        unsigned int dd = (unsigned int)min(hist[dl], 32767);
        csr[e0 + pos] = (unsigned int)sd.x | (dd << 17);
    }
}

// ---------------- finalize weights: |w| = dinv[s]*rsqrt(deg_d), 15-bit fixed-point ----------------
__global__ void k_weights(unsigned int* __restrict__ csr, const float* __restrict__ dinv, int E) {
    int e = blockIdx.x * blockDim.x + threadIdx.x;
    if (e < E) {
        unsigned int v = csr[e];
        unsigned int s = v & SRCMASK;
        float dd = rsqrtf((float)(v >> 17));      // deg_d >= 1 for existing edges
        float aw = dinv[s] * dd;                  // in [0,1]
        unsigned int qw = (unsigned int)(aw * QW_SCALE + 0.5f);
        csr[e] = s | (qw << 17);
    }
}

// per-edge accumulate helper
__device__ __forceinline__ void edge_acc(const __half* __restrict__ h, unsigned int v,
                                         int li, float& sw, float (&acc)[8]) {
    uint4 a = *(const uint4*)(h + (size_t)(v & SRCMASK) * NCH + li * 8);
    float w = -(float)(v >> 17) * QW_INV;
    sw += w;
    float2 f;
    f = __half22float2(*(__half2*)&a.x); acc[0] = fmaf(w, f.x, acc[0]); acc[1] = fmaf(w, f.y, acc[1]);
    f = __half22float2(*(__half2*)&a.y); acc[2] = fmaf(w, f.x, acc[2]); acc[3] = fmaf(w, f.y, acc[3]);
    f = __half22float2(*(__half2*)&a.z); acc[4] = fmaf(w, f.x, acc[4]); acc[5] = fmaf(w, f.y, acc[5]);
    f = __half22float2(*(__half2*)&a.w); acc[6] = fmaf(w, f.x, acc[6]); acc[7] = fmaf(w, f.y, acc[7]);
}

// ---------------- propagation: y = [2*]prop(gnorm(h)) [- tnorm(tx0)] ----------------
// Wave = 8 dst nodes; 8-lane group per node; lane owns 8 fixed channels (16B).
// One dwordx4 gather serves 8 edges; unroll x4 keeps 4 gathers in flight.
__global__ __launch_bounds__(256) void k_prop(const __half* __restrict__ h,
                                              const int* __restrict__ rowstart,
                                              const unsigned int* __restrict__ csr,
                                              const __half* __restrict__ tx0,
                                              __half* __restrict__ y, int N,
                                              const float* __restrict__ gstats,
                                              const float* __restrict__ tstats) {
    int lane = threadIdx.x & 63;
    int wv = (blockIdx.x * 256 + threadIdx.x) >> 6;
    int g = lane >> 3, li = lane & 7;
    int node = wv * 8 + g;
    int e = 0, e1 = 0;
    if (node < N) { e = rowstart[node]; e1 = rowstart[node + 1]; }
    float acc[8] = {0.f, 0.f, 0.f, 0.f, 0.f, 0.f, 0.f, 0.f};
    float sw = 0.0f;
    for (; e + 4 <= e1; e += 4) {
        unsigned int v0 = csr[e], v1 = csr[e + 1], v2 = csr[e + 2], v3 = csr[e + 3];
        uint4 a0 = *(const uint4*)(h + (size_t)(v0 & SRCMASK) * NCH + li * 8);
        uint4 a1 = *(const uint4*)(h + (size_t)(v1 & SRCMASK) * NCH + li * 8);
        uint4 a2 = *(const uint4*)(h + (size_t)(v2 & SRCMASK) * NCH + li * 8);
        uint4 a3 = *(const uint4*)(h + (size_t)(v3 & SRCMASK) * NCH + li * 8);
        float w0 = -(float)(v0 >> 17) * QW_INV;
        float w1 = -(float)(v1 >> 17) * QW_INV;
        float w2 = -(float)(v2 >> 17) * QW_INV;
        float w3 = -(float)(v3 >> 17) * QW_INV;
        sw += (w0 + w1) + (w2 + w3);
        float2 f;
        f = __half22float2(*(__half2*)&a0.x); acc[0] = fmaf(w0, f.x, acc[0]); acc[1] = fmaf(w0, f.y, acc[1]);
        f = __half22float2(*(__half2*)&a0.y); acc[2] = fmaf(w0, f.x, acc[2]); acc[3] = fmaf(w0, f.y, acc[3]);
        f = __half22float2(*(__half2*)&a0.z); acc[4] = fmaf(w0, f.x, acc[4]); acc[5] = fmaf(w0, f.y, acc[5]);
        f = __half22float2(*(__half2*)&a0.w); acc[6] = fmaf(w0, f.x, acc[6]); acc[7] = fmaf(w0, f.y, acc[7]);
        f = __half22float2(*(__half2*)&a1.x); acc[0] = fmaf(w1, f.x, acc[0]); acc[1] = fmaf(w1, f.y, acc[1]);
        f = __half22float2(*(__half2*)&a1.y); acc[2] = fmaf(w1, f.x, acc[2]); acc[3] = fmaf(w1, f.y, acc[3]);
        f = __half22float2(*(__half2*)&a1.z); acc[4] = fmaf(w1, f.x, acc[4]); acc[5] = fmaf(w1, f.y, acc[5]);
        f = __half22float2(*(__half2*)&a1.w); acc[6] = fmaf(w1, f.x, acc[6]); acc[7] = fmaf(w1, f.y, acc[7]);
        f = __half22float2(*(__half2*)&a2.x); acc[0] = fmaf(w2, f.x, acc[0]); acc[1] = fmaf(w2, f.y, acc[1]);
        f = __half22float2(*(__half2*)&a2.y); acc[2] = fmaf(w2, f.x, acc[2]); acc[3] = fmaf(w2, f.y, acc[3]);
        f = __half22float2(*(__half2*)&a2.z); acc[4] = fmaf(w2, f.x, acc[4]); acc[5] = fmaf(w2, f.y, acc[5]);
        f = __half22float2(*(__half2*)&a2.w); acc[6] = fmaf(w2, f.x, acc[6]); acc[7] = fmaf(w2, f.y, acc[7]);
        f = __half22float2(*(__half2*)&a3.x); acc[0] = fmaf(w3, f.x, acc[0]); acc[1] = fmaf(w3, f.y, acc[1]);
        f = __half22float2(*(__half2*)&a3.y); acc[2] = fmaf(w3, f.x, acc[2]); acc[3] = fmaf(w3, f.y, acc[3]);
        f = __half22float2(*(__half2*)&a3.z); acc[4] = fmaf(w3, f.x, acc[4]); acc[5] = fmaf(w3, f.y, acc[5]);
        f = __half22float2(*(__half2*)&a3.w); acc[6] = fmaf(w3, f.x, acc[6]); acc[7] = fmaf(w3, f.y, acc[7]);
    }
    for (; e < e1; e++) {
        unsigned int v = csr[e];
        edge_acc(h, v, li, sw, acc);
    }
    if (node >= N) return;
    if (gstats != nullptr) {
        float4 m0 = *(const float4*)(gstats + li * 8);
        float4 m1 = *(const float4*)(gstats + li * 8 + 4);
        float4 r0 = *(const float4*)(gstats + 64 + li * 8);
        float4 r1 = *(const float4*)(gstats + 64 + li * 8 + 4);
        acc[0] = r0.x * (acc[0] - m0.x * sw);
        acc[1] = r0.y * (acc[1] - m0.y * sw);
        acc[2] = r0.z * (acc[2] - m0.z * sw);
        acc[3] = r0.w * (acc[3] - m0.w * sw);
        acc[4] = r1.x * (acc[4] - m1.x * sw);
        acc[5] = r1.y * (acc[5] - m1.y * sw);
        acc[6] = r1.z * (acc[6] - m1.z * sw);
        acc[7] = r1.w * (acc[7] - m1.w * sw);
    }
    if (tx0 != nullptr) {
        uint4 tq = *(const uint4*)(tx0 + (size_t)node * NCH + li * 8);
        float tv[8];
        float2 f;
        f = __half22float2(*(__half2*)&tq.x); tv[0] = f.x; tv[1] = f.y;
        f = __half22float2(*(__half2*)&tq.y); tv[2] = f.x; tv[3] = f.y;
        f = __half22float2(*(__half2*)&tq.z); tv[4] = f.x; tv[5] = f.y;
        f = __half22float2(*(__half2*)&tq.w); tv[6] = f.x; tv[7] = f.y;
        if (tstats != nullptr) {
            float4 m0 = *(const float4*)(tstats + li * 8);
            float4 m1 = *(const float4*)(tstats + li * 8 + 4);
            float4 r0 = *(const float4*)(tstats + 64 + li * 8);
            float4 r1 = *(const float4*)(tstats + 64 + li * 8 + 4);
            tv[0] = (tv[0] - m0.x) * r0.x; tv[1] = (tv[1] - m0.y) * r0.y;
            tv[2] = (tv[2] - m0.z) * r0.z; tv[3] = (tv[3] - m0.w) * r0.w;
            tv[4] = (tv[4] - m1.x) * r1.x; tv[5] = (tv[5] - m1.y) * r1.y;
            tv[6] = (tv[6] - m1.z) * r1.z; tv[7] = (tv[7] - m1.w) * r1.w;
        }
#pragma unroll
        for (int j = 0; j < 8; j++) acc[j] = 2.0f * acc[j] - tv[j];
    }
    uint4 o;
    __half2 hh;
    hh = __floats2half2_rn(acc[0], acc[1]); o.x = *(unsigned int*)&hh;
    hh = __floats2half2_rn(acc[2], acc[3]); o.y = *(unsigned int*)&hh;
    hh = __floats2half2_rn(acc[4], acc[5]); o.z = *(unsigned int*)&hh;
    hh = __floats2half2_rn(acc[6], acc[7]); o.w = *(unsigned int*)&hh;
    *(uint4*)(y + (size_t)node * NCH + li * 8) = o;
}

// ---------------- MFMA dense combine + bias + ReLU + banked instance-norm stats ----------------
// One wave per 16 nodes; [16x192]@[192x64] via 6 K-steps x 4 N-tiles of
// mfma_f32_16x16x32_f16. tstats (optional) normalizes the tx0 input on the fly.
template <typename TOUT>
__global__ __launch_bounds__(256) void k_dmm(const __half* __restrict__ tx0,
                                             const __half* __restrict__ tx1,
                                             const __half* __restrict__ tx2,
                                             const _Float16* __restrict__ Wb,
                                             const float* __restrict__ b,
                                             TOUT* __restrict__ out,
                                             float* __restrict__ statsP, int N,
                                             const float* __restrict__ tstats) {
    __shared__ float sred[64];
    __shared__ float sq[64];
    int t = threadIdx.x;
    int w = t >> 6;
    int lane = t & 63;
    if (t < 64) { sred[t] = 0.f; sq[t] = 0.f; }
    __syncthreads();

    int nb16 = blockIdx.x * 64 + w * 16;
    int m = lane & 15, q = lane >> 4;
    int row = nb16 + m;
    int rowC = (row < N) ? row : 0;
    const __half* base0 = tx0 + (size_t)rowC * NCH;
    const __half* base1 = tx1 + (size_t)rowC * NCH;
    const __half* base2 = tx2 + (size_t)rowC * NCH;

    f32x4 acc[4];
#pragma unroll
    for (int tile = 0; tile < 4; tile++) acc[tile] = (f32x4){0.f, 0.f, 0.f, 0.f};

#pragma unroll
    for (int kk = 0; kk < 6; kk++) {
        const __half* ap = (kk < 2 ? base0 : (kk < 4 ? base1 : base2)) + (kk & 1) * 32 + q * 8;
        f16x8 a = *(const f16x8*)ap;
        if (kk < 2 && tstats != nullptr) {
            int cbase = (kk & 1) * 32 + q * 8;
#pragma unroll
            for (int j = 0; j < 8; j++) {
                float v = (float)a[j];
                a[j] = (_Float16)((v - tstats[cbase + j]) * tstats[64 + cbase + j]);
            }
        }
#pragma unroll
        for (int tile = 0; tile < 4; tile++) {
            f16x8 bf = *(const f16x8*)(Wb + ((size_t)(tile * 6 + kk) * 64 + lane) * 8);
            acc[tile] = __builtin_amdgcn_mfma_f32_16x16x32_f16(a, bf, acc[tile], 0, 0, 0);
        }
    }

#pragma unroll
    for (int tile = 0; tile < 4; tile++) {
        int ch = tile * 16 + m;
        float bb = b[ch];
        float s = 0.f, qq = 0.f;
#pragma unroll
        for (int r = 0; r < 4; r++) {
            int node = nb16 + q * 4 + r;
            float v = fmaxf(acc[tile][r] + bb, 0.f);
            if (node < N) {
                out[(size_t)node * NCH + ch] = (TOUT)v;
                s += v;
                qq = fmaf(v, v, qq);
            }
        }
        s += __shfl_xor(s, 16, 64);  s += __shfl_xor(s, 32, 64);
        qq += __shfl_xor(qq, 16, 64); qq += __shfl_xor(qq, 32, 64);
        if (q == 0) { atomicAdd(&sred[ch], s); atomicAdd(&sq[ch], qq); }
    }
    __syncthreads();
    if (t < 64) {
        int bank = blockIdx.x & (SBANKS - 1);
        atomicAdd(&statsP[bank * 128 + t], sred[t]);
        atomicAdd(&statsP[bank * 128 + 64 + t], sq[t]);
    }
}

__global__ void k_final(float* __restrict__ statsP, float invN) {
    int c = threadIdx.x;  // 64
    float S = 0.f, Q = 0.f;
    for (int k = 0; k < SBANKS; k++) {
        S += statsP[k * 128 + c];
        Q += statsP[k * 128 + 64 + c];
    }
    float m = S * invN;
    float var = Q * invN - m * m;
    statsP[SBANKS * 128 + c] = m;
    statsP[SBANKS * 128 + 64 + c] = rsqrtf(var + EPS);
}

// normalize fp16 A -> fp32 out
__global__ void k_norm_hf(const __half* __restrict__ a, float* __restrict__ o,
                          const float* __restrict__ statsP, int total) {
    int i = blockIdx.x * blockDim.x + threadIdx.x;
    if (i >= total) return;
    int lane = i & 63;
    o[i] = (__half2float(a[i]) - statsP[SBANKS * 128 + lane]) * statsP[SBANKS * 128 + 64 + lane];
}

// ---------------- launcher ----------------
extern "C" void kernel_launch(void* const* d_in, const int* in_sizes, int n_in,
                              void* d_out, int out_size, void* d_ws, size_t ws_size,
                              hipStream_t stream) {
    const float* x  = (const float*)d_in[0];
    const int*   ei = (const int*)d_in[1];
    const float* W1 = (const float*)d_in[2];
    const float* b1 = (const float*)d_in[3];
    const float* W2 = (const float*)d_in[4];
    const float* b2 = (const float*)d_in[5];
    float* out = (float*)d_out;

    const int N = in_sizes[0] / NCH;
    const int E = in_sizes[1] / 2;
    const int* src = ei;
    const int* dst = ei + E;
    const int nbuck = (N + 255) >> BSHIFT;

    // workspace carve (256B aligned)
    char* p = (char*)d_ws;
    auto alloc = [&](size_t bytes) {
        void* r = (void*)p;
        p += ((bytes + 255) / 256) * 256;
        return r;
    };
    float*  dinv     = (float*)alloc((size_t)N * 4);
    int*    rowstart = (int*)alloc((size_t)(N + 1) * 4);
    int*    cnt      = (int*)alloc((size_t)nbuck * 4);
    int*    gbase    = (int*)alloc((size_t)(nbuck + 1) * 4);
    int*    gcur     = (int*)alloc((size_t)nbuck * 4);
    unsigned int* csr = (unsigned int*)alloc((size_t)E * 4);
    __half* xh       = (__half*)alloc((size_t)N * NCH * 2);
    __half* Tx1      = (__half*)alloc((size_t)N * NCH * 2);
    __half* Tx2      = (__half*)alloc((size_t)N * NCH * 2);
    __half* A        = (__half*)alloc((size_t)N * NCH * 2);
    __half* A2       = (__half*)alloc((size_t)N * NCH * 2);
    _Float16* Wb1    = (_Float16*)alloc(12288 * 2);
    _Float16* Wb2    = (_Float16*)alloc(12288 * 2);
    const int statsFloats = SBANKS * 128 + 128;
    float*  stats    = (float*)alloc((size_t)2 * statsFloats * 4);  // stats1 | stats2
    float*  stats1 = stats;
    float*  stats2 = stats + statsFloats;
    const float* nrm1 = stats1 + SBANKS * 128;  // m[64], r[64] after k_final

    // binned aliases Tx1 (dead before first k_prop writes Tx1)
    int2* binned = (int2*)Tx1;

    hipMemsetAsync(cnt, 0, (size_t)nbuck * 4, stream);
    hipMemsetAsync(stats, 0, (size_t)2 * statsFloats * 4, stream);

    const int TB = 256;
    const int per = (E + NHIST - 1) / NHIST;
    const int castTotal = N * NCH;
    const int castB = (castTotal / 4 + TB - 1) / TB;
    k_front<<<castB + 96 + NHIST, TB, 0, stream>>>(x, xh, castTotal, castB,
                                                   W1, Wb1, W2, Wb2,
                                                   dst, cnt, E, per, nbuck);
    k_bscan<<<1, 512, 0, stream>>>(cnt, gbase, gcur, nbuck, E);
    k_bin<<<NHIST, TB, 0, stream>>>(src, dst, gcur, binned, E, per, nbuck);
    k_bucket<<<nbuck, TB, 0, stream>>>(binned, gbase, dinv, rowstart, csr, N, nbuck, E);
    k_weights<<<(E + TB - 1) / TB, TB, 0, stream>>>(csr, dinv, E);

    const int propWaves = (N + 7) / 8;
    const int propBlocks = (propWaves + 3) / 4;
    const int dmmBlocks = (N + 63) / 64;
    const int normBlocks = (N * NCH + TB - 1) / TB;
    const float invN = 1.0f / (float)N;

    // ---- layer 1 (raw x) ----
    k_prop<<<propBlocks, TB, 0, stream>>>(xh, rowstart, csr, nullptr, Tx1, N, nullptr, nullptr);
    k_prop<<<propBlocks, TB, 0, stream>>>(Tx1, rowstart, csr, xh, Tx2, N, nullptr, nullptr);
    k_dmm<__half><<<dmmBlocks, TB, 0, stream>>>(xh, Tx1, Tx2, Wb1, b1, A, stats1, N, nullptr);
    k_final<<<1, 64, 0, stream>>>(stats1, invN);

    // ---- layer 2 (A normalized on the fly via nrm1) ----
    k_prop<<<propBlocks, TB, 0, stream>>>(A, rowstart, csr, nullptr, Tx1, N, nrm1, nullptr);
    k_prop<<<propBlocks, TB, 0, stream>>>(Tx1, rowstart, csr, A, Tx2, N, nullptr, nrm1);
    k_dmm<__half><<<dmmBlocks, TB, 0, stream>>>(A, Tx1, Tx2, Wb2, b2, A2, stats2, N, nrm1);
    k_final<<<1, 64, 0, stream>>>(stats2, invN);
    k_norm_hf<<<normBlocks, TB, 0, stream>>>(A2, out, stats2, N * NCH);
}

// Round 10
// 341.231 us; speedup vs baseline: 1.0620x; 1.0620x over previous
//
#include <hip/hip_runtime.h>
#include <hip/hip_fp16.h>

#define NCH 64
#define EPS 1e-5f
#define SBANKS 32   // stats atomic banks
#define BSHIFT 8    // 256 dst nodes per bucket
#define NHIST 256   // blocks in hist pass (256 -> 16-edge runs in k_bin reservations)
#define BINCAP 6400 // max edges per k_bin block (LDS capacity)
#define SRCMASK 0x1FFFFu
#define QW_SCALE 32767.0f
#define QW_INV (1.0f/32767.0f)

typedef _Float16 f16x8 __attribute__((ext_vector_type(8)));
typedef float f32x4 __attribute__((ext_vector_type(4)));

// ---------------- fused front: x cast + W1/W2 pack + bucket histogram ----------------
__global__ __launch_bounds__(256) void k_front(const float* __restrict__ x, __half* __restrict__ xh,
                                               int castTotal, int castB,
                                               const float* __restrict__ W1, _Float16* __restrict__ Wb1,
                                               const float* __restrict__ W2, _Float16* __restrict__ Wb2,
                                               const int* __restrict__ dst, int* __restrict__ cnt,
                                               int E, int per, int nbuck) {
    int bid = blockIdx.x;
    if (bid < castB) {
        int i = (bid * 256 + threadIdx.x) * 4;
        if (i < castTotal) {
            float4 f = *(const float4*)(x + i);
            __half2* o = (__half2*)(xh + i);
            o[0] = __floats2half2_rn(f.x, f.y);
            o[1] = __floats2half2_rn(f.z, f.w);
        }
        return;
    }
    if (bid < castB + 96) {
        // W pack: Wb[((tile*6+kk)*64+lane)*8+j] = W[kk*32+(lane>>4)*8+j][tile*16+(lane&15)]
        int wb = bid - castB;
        const float* W = (wb < 48) ? W1 : W2;
        _Float16* Wb = (wb < 48) ? Wb1 : Wb2;
        int idx = (wb % 48) * 256 + threadIdx.x;   // 0..12287
        int j = idx & 7;
        int lane = (idx >> 3) & 63;
        int tk = idx >> 9;
        int tile = tk / 6, kk = tk % 6;
        int k = kk * 32 + (lane >> 4) * 8 + j;
        int n = tile * 16 + (lane & 15);
        Wb[idx] = (_Float16)W[k * 64 + n];
        return;
    }
    // histogram role
    __shared__ int lh[512];
    int hb = bid - castB - 96;
    for (int t = threadIdx.x; t < nbuck; t += 256) lh[t] = 0;
    __syncthreads();
    int lo = hb * per, hi = min(E, lo + per);
    for (int e = lo + threadIdx.x; e < hi; e += 256)
        atomicAdd(&lh[dst[e] >> BSHIFT], 1);
    __syncthreads();
    for (int t = threadIdx.x; t < nbuck; t += 256)
        if (lh[t]) atomicAdd(&cnt[t], lh[t]);
}

// ---------------- scan bucket counts -> base & cursor ----------------
__global__ void k_bscan(const int* __restrict__ cnt, int* __restrict__ gbase,
                        int* __restrict__ gcur, int nbuck, int E) {
    __shared__ int s[512];
    int t = threadIdx.x;
    int v = (t < nbuck) ? cnt[t] : 0;
    s[t] = v;
    __syncthreads();
    for (int off = 1; off < 512; off <<= 1) {
        int add = (t >= off) ? s[t - off] : 0;
        __syncthreads();
        s[t] += add;
        __syncthreads();
    }
    if (t < nbuck) { int ex = s[t] - v; gbase[t] = ex; gcur[t] = ex; }
    if (t == 0) gbase[nbuck] = E;
}

// ---------------- bin edges into bucket segments (LDS counting sort) ----------------
// Sort the block's edge slice by bucket in LDS, then stream runs out with
// coalesced full-line stores (fixes the scattered-8B-write amplification).
__global__ __launch_bounds__(256) void k_bin(const int* __restrict__ src,
                                             const int* __restrict__ dst,
                                             int* __restrict__ gcur,
                                             int2* __restrict__ binned, int E, int per, int nbuck) {
    __shared__ int lh[512];     // per-block bucket counts
    __shared__ int lsc[512];    // exclusive scan (local run starts)
    __shared__ int lbase[512];  // reserved global run bases
    __shared__ int lcur[512];   // scatter cursors
    __shared__ int2 sedge[BINCAP];
    int t = threadIdx.x;
    for (int i = t; i < 512; i += 256) lh[i] = 0;
    __syncthreads();
    int lo = blockIdx.x * per, hi = min(E, lo + per);
    for (int e = lo + t; e < hi; e += 256)
        atomicAdd(&lh[dst[e] >> BSHIFT], 1);
    __syncthreads();
    // inclusive scan over 512 with 256 threads (Hillis-Steele, 2 elems/thread)
    int v0 = lh[t], v1 = lh[t + 256];
    lsc[t] = v0; lsc[t + 256] = v1;
    __syncthreads();
    for (int off = 1; off < 512; off <<= 1) {
        int a0 = (t >= off) ? lsc[t - off] : 0;
        int a1 = (t + 256 >= off) ? lsc[t + 256 - off] : 0;
        __syncthreads();
        lsc[t] += a0; lsc[t + 256] += a1;
        __syncthreads();
    }
    // -> exclusive, reserve global runs, init cursors
    lsc[t] -= v0; lsc[t + 256] -= v1;
    if (t < nbuck && v0) lbase[t] = atomicAdd(&gcur[t], v0);
    if (t + 256 < nbuck && v1) lbase[t + 256] = atomicAdd(&gcur[t + 256], v1);
    lcur[t] = lsc[t]; lcur[t + 256] = lsc[t + 256];
    __syncthreads();
    // scatter into LDS at sorted position
    for (int e = lo + t; e < hi; e += 256) {
        int d = dst[e];
        int b = d >> BSHIFT;
        int pos = atomicAdd(&lcur[b], 1);
        sedge[pos] = make_int2(src[e], d);
    }
    __syncthreads();
    // stream out: consecutive i -> consecutive global addresses within each run
    int cntE = hi - lo;
    for (int i = t; i < cntE; i += 256) {
        int2 sd = sedge[i];
        int b = sd.y >> BSHIFT;
        binned[lbase[b] + (i - lsc[b])] = sd;
    }
}

// ---------------- per-bucket CSR build: entry = src(17b) | deg_d(15b) ----------------
__global__ __launch_bounds__(256) void k_bucket(const int2* __restrict__ binned,
                                                const int* __restrict__ gbase,
                                                float* __restrict__ dinv,
                                                int* __restrict__ rowstart,
                                                unsigned int* __restrict__ csr, int N, int nbuck, int E) {
    __shared__ int hist[256];
    __shared__ int lcur[256];
    __shared__ int ltmp[256];
    int b = blockIdx.x;
    int t = threadIdx.x;
    int nodeLo = b << BSHIFT;
    int nHere = min(256, N - nodeLo);
    int e0 = gbase[b], e1 = gbase[b + 1];
    hist[t] = 0;
    __syncthreads();
    for (int e = e0 + t; e < e1; e += 256)
        atomicAdd(&hist[binned[e].y - nodeLo], 1);
    __syncthreads();
    int deg = (t < nHere) ? hist[t] : 0;
    if (t < nHere) dinv[nodeLo + t] = (deg > 0) ? rsqrtf((float)deg) : 0.0f;
    ltmp[t] = deg;
    __syncthreads();
    for (int off = 1; off < 256; off <<= 1) {
        int add = (t >= off) ? ltmp[t - off] : 0;
        __syncthreads();
        ltmp[t] += add;
        __syncthreads();
    }
    int lstart = ltmp[t] - deg;
    if (t < nHere) rowstart[nodeLo + t] = e0 + lstart;
    if (b == nbuck - 1 && t == 0) rowstart[N] = E;
    lcur[t] = lstart;
    __syncthreads();
    for (int e = e0 + t; e < e1; e += 256) {
        int2 sd = binned[e];
        int dl = sd.y - nodeLo;
        int pos = atomicAdd(&lcur[dl], 1);
        unsigned int dd = (unsigned int)min(hist[dl], 32767);
        csr[e0 + pos] = (unsigned int)sd.x | (dd << 17);
    }
}

// ---------------- finalize weights: |w| = dinv[s]*rsqrt(deg_d), 15-bit fixed-point ----------------
__global__ void k_weights(unsigned int* __restrict__ csr, const float* __restrict__ dinv, int E) {
    int e = blockIdx.x * blockDim.x + threadIdx.x;
    if (e < E) {
        unsigned int v = csr[e];
        unsigned int s = v & SRCMASK;
        float dd = rsqrtf((float)(v >> 17));      // deg_d >= 1 for existing edges
        float aw = dinv[s] * dd;                  // in [0,1]
        unsigned int qw = (unsigned int)(aw * QW_SCALE + 0.5f);
        csr[e] = s | (qw << 17);
    }
}

// per-edge accumulate helper
__device__ __forceinline__ void edge_acc(const __half* __restrict__ h, unsigned int v,
                                         int li, float& sw, float (&acc)[8]) {
    uint4 a = *(const uint4*)(h + (size_t)(v & SRCMASK) * NCH + li * 8);
    float w = -(float)(v >> 17) * QW_INV;
    sw += w;
    float2 f;
    f = __half22float2(*(__half2*)&a.x); acc[0] = fmaf(w, f.x, acc[0]); acc[1] = fmaf(w, f.y, acc[1]);
    f = __half22float2(*(__half2*)&a.y); acc[2] = fmaf(w, f.x, acc[2]); acc[3] = fmaf(w, f.y, acc[3]);
    f = __half22float2(*(__half2*)&a.z); acc[4] = fmaf(w, f.x, acc[4]); acc[5] = fmaf(w, f.y, acc[5]);
    f = __half22float2(*(__half2*)&a.w); acc[6] = fmaf(w, f.x, acc[6]); acc[7] = fmaf(w, f.y, acc[7]);
}

// ---------------- propagation: y = [2*]prop(gnorm(h)) [- tnorm(tx0)] ----------------
// Wave = 8 dst nodes; 8-lane group per node; lane owns 8 fixed channels (16B).
// One dwordx4 gather serves 8 edges; unroll x4 keeps 4 gathers in flight.
__global__ __launch_bounds__(256) void k_prop(const __half* __restrict__ h,
                                              const int* __restrict__ rowstart,
                                              const unsigned int* __restrict__ csr,
                                              const __half* __restrict__ tx0,
                                              __half* __restrict__ y, int N,
                                              const float* __restrict__ gstats,
                                              const float* __restrict__ tstats) {
    int lane = threadIdx.x & 63;
    int wv = (blockIdx.x * 256 + threadIdx.x) >> 6;
    int g = lane >> 3, li = lane & 7;
    int node = wv * 8 + g;
    int e = 0, e1 = 0;
    if (node < N) { e = rowstart[node]; e1 = rowstart[node + 1]; }
    float acc[8] = {0.f, 0.f, 0.f, 0.f, 0.f, 0.f, 0.f, 0.f};
    float sw = 0.0f;
    for (; e + 4 <= e1; e += 4) {
        unsigned int v0 = csr[e], v1 = csr[e + 1], v2 = csr[e + 2], v3 = csr[e + 3];
        uint4 a0 = *(const uint4*)(h + (size_t)(v0 & SRCMASK) * NCH + li * 8);
        uint4 a1 = *(const uint4*)(h + (size_t)(v1 & SRCMASK) * NCH + li * 8);
        uint4 a2 = *(const uint4*)(h + (size_t)(v2 & SRCMASK) * NCH + li * 8);
        uint4 a3 = *(const uint4*)(h + (size_t)(v3 & SRCMASK) * NCH + li * 8);
        float w0 = -(float)(v0 >> 17) * QW_INV;
        float w1 = -(float)(v1 >> 17) * QW_INV;
        float w2 = -(float)(v2 >> 17) * QW_INV;
        float w3 = -(float)(v3 >> 17) * QW_INV;
        sw += (w0 + w1) + (w2 + w3);
        float2 f;
        f = __half22float2(*(__half2*)&a0.x); acc[0] = fmaf(w0, f.x, acc[0]); acc[1] = fmaf(w0, f.y, acc[1]);
        f = __half22float2(*(__half2*)&a0.y); acc[2] = fmaf(w0, f.x, acc[2]); acc[3] = fmaf(w0, f.y, acc[3]);
        f = __half22float2(*(__half2*)&a0.z); acc[4] = fmaf(w0, f.x, acc[4]); acc[5] = fmaf(w0, f.y, acc[5]);
        f = __half22float2(*(__half2*)&a0.w); acc[6] = fmaf(w0, f.x, acc[6]); acc[7] = fmaf(w0, f.y, acc[7]);
        f = __half22float2(*(__half2*)&a1.x); acc[0] = fmaf(w1, f.x, acc[0]); acc[1] = fmaf(w1, f.y, acc[1]);
        f = __half22float2(*(__half2*)&a1.y); acc[2] = fmaf(w1, f.x, acc[2]); acc[3] = fmaf(w1, f.y, acc[3]);
        f = __half22float2(*(__half2*)&a1.z); acc[4] = fmaf(w1, f.x, acc[4]); acc[5] = fmaf(w1, f.y, acc[5]);
        f = __half22float2(*(__half2*)&a1.w); acc[6] = fmaf(w1, f.x, acc[6]); acc[7] = fmaf(w1, f.y, acc[7]);
        f = __half22float2(*(__half2*)&a2.x); acc[0] = fmaf(w2, f.x, acc[0]); acc[1] = fmaf(w2, f.y, acc[1]);
        f = __half22float2(*(__half2*)&a2.y); acc[2] = fmaf(w2, f.x, acc[2]); acc[3] = fmaf(w2, f.y, acc[3]);
        f = __half22float2(*(__half2*)&a2.z); acc[4] = fmaf(w2, f.x, acc[4]); acc[5] = fmaf(w2, f.y, acc[5]);
        f = __half22float2(*(__half2*)&a2.w); acc[6] = fmaf(w2, f.x, acc[6]); acc[7] = fmaf(w2, f.y, acc[7]);
        f = __half22float2(*(__half2*)&a3.x); acc[0] = fmaf(w3, f.x, acc[0]); acc[1] = fmaf(w3, f.y, acc[1]);
        f = __half22float2(*(__half2*)&a3.y); acc[2] = fmaf(w3, f.x, acc[2]); acc[3] = fmaf(w3, f.y, acc[3]);
        f = __half22float2(*(__half2*)&a3.z); acc[4] = fmaf(w3, f.x, acc[4]); acc[5] = fmaf(w3, f.y, acc[5]);
        f = __half22float2(*(__half2*)&a3.w); acc[6] = fmaf(w3, f.x, acc[6]); acc[7] = fmaf(w3, f.y, acc[7]);
    }
    for (; e < e1; e++) {
        unsigned int v = csr[e];
        edge_acc(h, v, li, sw, acc);
    }
    if (node >= N) return;
    if (gstats != nullptr) {
        float4 m0 = *(const float4*)(gstats + li * 8);
        float4 m1 = *(const float4*)(gstats + li * 8 + 4);
        float4 r0 = *(const float4*)(gstats + 64 + li * 8);
        float4 r1 = *(const float4*)(gstats + 64 + li * 8 + 4);
        acc[0] = r0.x * (acc[0] - m0.x * sw);
        acc[1] = r0.y * (acc[1] - m0.y * sw);
        acc[2] = r0.z * (acc[2] - m0.z * sw);
        acc[3] = r0.w * (acc[3] - m0.w * sw);
        acc[4] = r1.x * (acc[4] - m1.x * sw);
        acc[5] = r1.y * (acc[5] - m1.y * sw);
        acc[6] = r1.z * (acc[6] - m1.z * sw);
        acc[7] = r1.w * (acc[7] - m1.w * sw);
    }
    if (tx0 != nullptr) {
        uint4 tq = *(const uint4*)(tx0 + (size_t)node * NCH + li * 8);
        float tv[8];
        float2 f;
        f = __half22float2(*(__half2*)&tq.x); tv[0] = f.x; tv[1] = f.y;
        f = __half22float2(*(__half2*)&tq.y); tv[2] = f.x; tv[3] = f.y;
        f = __half22float2(*(__half2*)&tq.z); tv[4] = f.x; tv[5] = f.y;
        f = __half22float2(*(__half2*)&tq.w); tv[6] = f.x; tv[7] = f.y;
        if (tstats != nullptr) {
            float4 m0 = *(const float4*)(tstats + li * 8);
            float4 m1 = *(const float4*)(tstats + li * 8 + 4);
            float4 r0 = *(const float4*)(tstats + 64 + li * 8);
            float4 r1 = *(const float4*)(tstats + 64 + li * 8 + 4);
            tv[0] = (tv[0] - m0.x) * r0.x; tv[1] = (tv[1] - m0.y) * r0.y;
            tv[2] = (tv[2] - m0.z) * r0.z; tv[3] = (tv[3] - m0.w) * r0.w;
            tv[4] = (tv[4] - m1.x) * r1.x; tv[5] = (tv[5] - m1.y) * r1.y;
            tv[6] = (tv[6] - m1.z) * r1.z; tv[7] = (tv[7] - m1.w) * r1.w;
        }
#pragma unroll
        for (int j = 0; j < 8; j++) acc[j] = 2.0f * acc[j] - tv[j];
    }
    uint4 o;
    __half2 hh;
    hh = __floats2half2_rn(acc[0], acc[1]); o.x = *(unsigned int*)&hh;
    hh = __floats2half2_rn(acc[2], acc[3]); o.y = *(unsigned int*)&hh;
    hh = __floats2half2_rn(acc[4], acc[5]); o.z = *(unsigned int*)&hh;
    hh = __floats2half2_rn(acc[6], acc[7]); o.w = *(unsigned int*)&hh;
    *(uint4*)(y + (size_t)node * NCH + li * 8) = o;
}

// ---------------- MFMA dense combine + bias + ReLU + banked instance-norm stats ----------------
// One wave per 16 nodes; [16x192]@[192x64] via 6 K-steps x 4 N-tiles of
// mfma_f32_16x16x32_f16. tstats (optional) normalizes the tx0 input on the fly.
template <typename TOUT>
__global__ __launch_bounds__(256) void k_dmm(const __half* __restrict__ tx0,
                                             const __half* __restrict__ tx1,
                                             const __half* __restrict__ tx2,
                                             const _Float16* __restrict__ Wb,
                                             const float* __restrict__ b,
                                             TOUT* __restrict__ out,
                                             float* __restrict__ statsP, int N,
                                             const float* __restrict__ tstats) {
    __shared__ float sred[64];
    __shared__ float sq[64];
    int t = threadIdx.x;
    int w = t >> 6;
    int lane = t & 63;
    if (t < 64) { sred[t] = 0.f; sq[t] = 0.f; }
    __syncthreads();

    int nb16 = blockIdx.x * 64 + w * 16;
    int m = lane & 15, q = lane >> 4;
    int row = nb16 + m;
    int rowC = (row < N) ? row : 0;
    const __half* base0 = tx0 + (size_t)rowC * NCH;
    const __half* base1 = tx1 + (size_t)rowC * NCH;
    const __half* base2 = tx2 + (size_t)rowC * NCH;

    f32x4 acc[4];
#pragma unroll
    for (int tile = 0; tile < 4; tile++) acc[tile] = (f32x4){0.f, 0.f, 0.f, 0.f};

#pragma unroll
    for (int kk = 0; kk < 6; kk++) {
        const __half* ap = (kk < 2 ? base0 : (kk < 4 ? base1 : base2)) + (kk & 1) * 32 + q * 8;
        f16x8 a = *(const f16x8*)ap;
        if (kk < 2 && tstats != nullptr) {
            int cbase = (kk & 1) * 32 + q * 8;
#pragma unroll
            for (int j = 0; j < 8; j++) {
                float v = (float)a[j];
                a[j] = (_Float16)((v - tstats[cbase + j]) * tstats[64 + cbase + j]);
            }
        }
#pragma unroll
        for (int tile = 0; tile < 4; tile++) {
            f16x8 bf = *(const f16x8*)(Wb + ((size_t)(tile * 6 + kk) * 64 + lane) * 8);
            acc[tile] = __builtin_amdgcn_mfma_f32_16x16x32_f16(a, bf, acc[tile], 0, 0, 0);
        }
    }

#pragma unroll
    for (int tile = 0; tile < 4; tile++) {
        int ch = tile * 16 + m;
        float bb = b[ch];
        float s = 0.f, qq = 0.f;
#pragma unroll
        for (int r = 0; r < 4; r++) {
            int node = nb16 + q * 4 + r;
            float v = fmaxf(acc[tile][r] + bb, 0.f);
            if (node < N) {
                out[(size_t)node * NCH + ch] = (TOUT)v;
                s += v;
                qq = fmaf(v, v, qq);
            }
        }
        s += __shfl_xor(s, 16, 64);  s += __shfl_xor(s, 32, 64);
        qq += __shfl_xor(qq, 16, 64); qq += __shfl_xor(qq, 32, 64);
        if (q == 0) { atomicAdd(&sred[ch], s); atomicAdd(&sq[ch], qq); }
    }
    __syncthreads();
    if (t < 64) {
        int bank = blockIdx.x & (SBANKS - 1);
        atomicAdd(&statsP[bank * 128 + t], sred[t]);
        atomicAdd(&statsP[bank * 128 + 64 + t], sq[t]);
    }
}

__global__ void k_final(float* __restrict__ statsP, float invN) {
    int c = threadIdx.x;  // 64
    float S = 0.f, Q = 0.f;
    for (int k = 0; k < SBANKS; k++) {
        S += statsP[k * 128 + c];
        Q += statsP[k * 128 + 64 + c];
    }
    float m = S * invN;
    float var = Q * invN - m * m;
    statsP[SBANKS * 128 + c] = m;
    statsP[SBANKS * 128 + 64 + c] = rsqrtf(var + EPS);
}

// normalize fp16 A -> fp32 out
__global__ void k_norm_hf(const __half* __restrict__ a, float* __restrict__ o,
                          const float* __restrict__ statsP, int total) {
    int i = blockIdx.x * blockDim.x + threadIdx.x;
    if (i >= total) return;
    int lane = i & 63;
    o[i] = (__half2float(a[i]) - statsP[SBANKS * 128 + lane]) * statsP[SBANKS * 128 + 64 + lane];
}

// ---------------- launcher ----------------
extern "C" void kernel_launch(void* const* d_in, const int* in_sizes, int n_in,
                              void* d_out, int out_size, void* d_ws, size_t ws_size,
                              hipStream_t stream) {
    const float* x  = (const float*)d_in[0];
    const int*   ei = (const int*)d_in[1];
    const float* W1 = (const float*)d_in[2];
    const float* b1 = (const float*)d_in[3];
    const float* W2 = (const float*)d_in[4];
    const float* b2 = (const float*)d_in[5];
    float* out = (float*)d_out;

    const int N = in_sizes[0] / NCH;
    const int E = in_sizes[1] / 2;
    const int* src = ei;
    const int* dst = ei + E;
    const int nbuck = (N + 255) >> BSHIFT;

    // workspace carve (256B aligned)
    char* p = (char*)d_ws;
    auto alloc = [&](size_t bytes) {
        void* r = (void*)p;
        p += ((bytes + 255) / 256) * 256;
        return r;
    };
    float*  dinv     = (float*)alloc((size_t)N * 4);
    int*    rowstart = (int*)alloc((size_t)(N + 1) * 4);
    int*    cnt      = (int*)alloc((size_t)nbuck * 4);
    int*    gbase    = (int*)alloc((size_t)(nbuck + 1) * 4);
    int*    gcur     = (int*)alloc((size_t)nbuck * 4);
    unsigned int* csr = (unsigned int*)alloc((size_t)E * 4);
    __half* xh       = (__half*)alloc((size_t)N * NCH * 2);
    __half* Tx1      = (__half*)alloc((size_t)N * NCH * 2);
    __half* Tx2      = (__half*)alloc((size_t)N * NCH * 2);
    __half* A        = (__half*)alloc((size_t)N * NCH * 2);
    __half* A2       = (__half*)alloc((size_t)N * NCH * 2);
    _Float16* Wb1    = (_Float16*)alloc(12288 * 2);
    _Float16* Wb2    = (_Float16*)alloc(12288 * 2);
    const int statsFloats = SBANKS * 128 + 128;
    float*  stats    = (float*)alloc((size_t)2 * statsFloats * 4);  // stats1 | stats2
    float*  stats1 = stats;
    float*  stats2 = stats + statsFloats;
    const float* nrm1 = stats1 + SBANKS * 128;  // m[64], r[64] after k_final

    // binned aliases Tx1 (dead before first k_prop writes Tx1)
    int2* binned = (int2*)Tx1;

    hipMemsetAsync(cnt, 0, (size_t)nbuck * 4, stream);
    hipMemsetAsync(stats, 0, (size_t)2 * statsFloats * 4, stream);

    const int TB = 256;
    // k_bin blocks: keep slices within LDS capacity, prefer 256 (128B runs/bucket)
    int nbin = (E + BINCAP - 1) / BINCAP;
    if (nbin < 256) nbin = 256;
    const int perBin = (E + nbin - 1) / nbin;
    const int perH = (E + NHIST - 1) / NHIST;
    const int castTotal = N * NCH;
    const int castB = (castTotal / 4 + TB - 1) / TB;
    k_front<<<castB + 96 + NHIST, TB, 0, stream>>>(x, xh, castTotal, castB,
                                                   W1, Wb1, W2, Wb2,
                                                   dst, cnt, E, perH, nbuck);
    k_bscan<<<1, 512, 0, stream>>>(cnt, gbase, gcur, nbuck, E);
    k_bin<<<nbin, TB, 0, stream>>>(src, dst, gcur, binned, E, perBin, nbuck);
    k_bucket<<<nbuck, TB, 0, stream>>>(binned, gbase, dinv, rowstart, csr, N, nbuck, E);
    k_weights<<<(E + TB - 1) / TB, TB, 0, stream>>>(csr, dinv, E);

    const int propWaves = (N + 7) / 8;
    const int propBlocks = (propWaves + 3) / 4;
    const int dmmBlocks = (N + 63) / 64;
    const int normBlocks = (N * NCH + TB - 1) / TB;
    const float invN = 1.0f / (float)N;

    // ---- layer 1 (raw x) ----
    k_prop<<<propBlocks, TB, 0, stream>>>(xh, rowstart, csr, nullptr, Tx1, N, nullptr, nullptr);
    k_prop<<<propBlocks, TB, 0, stream>>>(Tx1, rowstart, csr, xh, Tx2, N, nullptr, nullptr);
    k_dmm<__half><<<dmmBlocks, TB, 0, stream>>>(xh, Tx1, Tx2, Wb1, b1, A, stats1, N, nullptr);
    k_final<<<1, 64, 0, stream>>>(stats1, invN);

    // ---- layer 2 (A normalized on the fly via nrm1) ----
    k_prop<<<propBlocks, TB, 0, stream>>>(A, rowstart, csr, nullptr, Tx1, N, nrm1, nullptr);
    k_prop<<<propBlocks, TB, 0, stream>>>(Tx1, rowstart, csr, A, Tx2, N, nullptr, nrm1);
    k_dmm<__half><<<dmmBlocks, TB, 0, stream>>>(A, Tx1, Tx2, Wb2, b2, A2, stats2, N, nrm1);
    k_final<<<1, 64, 0, stream>>>(stats2, invN);
    k_norm_hf<<<normBlocks, TB, 0, stream>>>(A2, out, stats2, N * NCH);
}

// Round 11
// 333.522 us; speedup vs baseline: 1.0866x; 1.0231x over previous
//
#include <hip/hip_runtime.h>
#include <hip/hip_fp16.h>

#define NCH 64
#define EPS 1e-5f
#define SBANKS 32   // stats atomic banks
#define BSHIFT 8    // 256 dst nodes per bucket
#define NHIST 256   // blocks in hist pass
#define BINCAP 6400 // max edges per k_bin block (LDS capacity)
#define PADRES 2048 // per-bucket csr slack for 8-padding (256*7 + align < 2048)
#define SRCMASK 0x1FFFFu
#define QW_SCALE 32767.0f
#define QW_INV (1.0f/32767.0f)

typedef _Float16 f16x8 __attribute__((ext_vector_type(8)));
typedef float f32x4 __attribute__((ext_vector_type(4)));

// ---------------- fused front: x cast + W1/W2 pack + bucket histogram ----------------
__global__ __launch_bounds__(256) void k_front(const float* __restrict__ x, __half* __restrict__ xh,
                                               int castTotal, int castB,
                                               const float* __restrict__ W1, _Float16* __restrict__ Wb1,
                                               const float* __restrict__ W2, _Float16* __restrict__ Wb2,
                                               const int* __restrict__ dst, int* __restrict__ cnt,
                                               int E, int per, int nbuck) {
    int bid = blockIdx.x;
    if (bid < castB) {
        int i = (bid * 256 + threadIdx.x) * 4;
        if (i < castTotal) {
            float4 f = *(const float4*)(x + i);
            __half2* o = (__half2*)(xh + i);
            o[0] = __floats2half2_rn(f.x, f.y);
            o[1] = __floats2half2_rn(f.z, f.w);
        }
        return;
    }
    if (bid < castB + 96) {
        // W pack: Wb[((tile*6+kk)*64+lane)*8+j] = W[kk*32+(lane>>4)*8+j][tile*16+(lane&15)]
        int wb = bid - castB;
        const float* W = (wb < 48) ? W1 : W2;
        _Float16* Wb = (wb < 48) ? Wb1 : Wb2;
        int idx = (wb % 48) * 256 + threadIdx.x;   // 0..12287
        int j = idx & 7;
        int lane = (idx >> 3) & 63;
        int tk = idx >> 9;
        int tile = tk / 6, kk = tk % 6;
        int k = kk * 32 + (lane >> 4) * 8 + j;
        int n = tile * 16 + (lane & 15);
        Wb[idx] = (_Float16)W[k * 64 + n];
        return;
    }
    // histogram role
    __shared__ int lh[512];
    int hb = bid - castB - 96;
    for (int t = threadIdx.x; t < nbuck; t += 256) lh[t] = 0;
    __syncthreads();
    int lo = hb * per, hi = min(E, lo + per);
    for (int e = lo + threadIdx.x; e < hi; e += 256)
        atomicAdd(&lh[dst[e] >> BSHIFT], 1);
    __syncthreads();
    for (int t = threadIdx.x; t < nbuck; t += 256)
        if (lh[t]) atomicAdd(&cnt[t], lh[t]);
}

// ---------------- scan bucket counts -> base & cursor ----------------
__global__ void k_bscan(const int* __restrict__ cnt, int* __restrict__ gbase,
                        int* __restrict__ gcur, int nbuck, int E) {
    __shared__ int s[512];
    int t = threadIdx.x;
    int v = (t < nbuck) ? cnt[t] : 0;
    s[t] = v;
    __syncthreads();
    for (int off = 1; off < 512; off <<= 1) {
        int add = (t >= off) ? s[t - off] : 0;
        __syncthreads();
        s[t] += add;
        __syncthreads();
    }
    if (t < nbuck) { int ex = s[t] - v; gbase[t] = ex; gcur[t] = ex; }
    if (t == 0) gbase[nbuck] = E;
}

// ---------------- bin edges into bucket segments (LDS counting sort) ----------------
__global__ __launch_bounds__(256) void k_bin(const int* __restrict__ src,
                                             const int* __restrict__ dst,
                                             int* __restrict__ gcur,
                                             int2* __restrict__ binned, int E, int per, int nbuck) {
    __shared__ int lh[512];     // per-block bucket counts
    __shared__ int lsc[512];    // exclusive scan (local run starts)
    __shared__ int lbase[512];  // reserved global run bases
    __shared__ int lcur[512];   // scatter cursors
    __shared__ int2 sedge[BINCAP];
    int t = threadIdx.x;
    for (int i = t; i < 512; i += 256) lh[i] = 0;
    __syncthreads();
    int lo = blockIdx.x * per, hi = min(E, lo + per);
    for (int e = lo + t; e < hi; e += 256)
        atomicAdd(&lh[dst[e] >> BSHIFT], 1);
    __syncthreads();
    int v0 = lh[t], v1 = lh[t + 256];
    lsc[t] = v0; lsc[t + 256] = v1;
    __syncthreads();
    for (int off = 1; off < 512; off <<= 1) {
        int a0 = (t >= off) ? lsc[t - off] : 0;
        int a1 = (t + 256 >= off) ? lsc[t + 256 - off] : 0;
        __syncthreads();
        lsc[t] += a0; lsc[t + 256] += a1;
        __syncthreads();
    }
    lsc[t] -= v0; lsc[t + 256] -= v1;
    if (t < nbuck && v0) lbase[t] = atomicAdd(&gcur[t], v0);
    if (t + 256 < nbuck && v1) lbase[t + 256] = atomicAdd(&gcur[t + 256], v1);
    lcur[t] = lsc[t]; lcur[t + 256] = lsc[t + 256];
    __syncthreads();
    for (int e = lo + t; e < hi; e += 256) {
        int d = dst[e];
        int b = d >> BSHIFT;
        int pos = atomicAdd(&lcur[b], 1);
        sedge[pos] = make_int2(src[e], d);
    }
    __syncthreads();
    int cntE = hi - lo;
    for (int i = t; i < cntE; i += 256) {
        int2 sd = sedge[i];
        int b = sd.y >> BSHIFT;
        binned[lbase[b] + (i - lsc[b])] = sd;
    }
}

// ---------------- per-bucket CSR build, rows padded to x8 edges ----------------
// rowinfo[node] = {csr start (8-aligned), padded deg}; padding slots replicate
// the row's first src with qw=0 (weight 0 -> no contribution, L1-hot gather).
__global__ __launch_bounds__(256) void k_bucket(const int2* __restrict__ binned,
                                                const int* __restrict__ gbase,
                                                float* __restrict__ dinv,
                                                int2* __restrict__ rowinfo,
                                                unsigned int* __restrict__ csr, int N, int nbuck) {
    __shared__ int hist[256];
    __shared__ int lcur[256];
    __shared__ int ltmp[256];
    int b = blockIdx.x;
    int t = threadIdx.x;
    int nodeLo = b << BSHIFT;
    int nHere = min(256, N - nodeLo);
    int e0 = gbase[b], e1 = gbase[b + 1];
    int pb = (gbase[b] + b * PADRES + 7) & ~7;   // 8-aligned padded base
    hist[t] = 0;
    __syncthreads();
    for (int e = e0 + t; e < e1; e += 256)
        atomicAdd(&hist[binned[e].y - nodeLo], 1);
    __syncthreads();
    int deg = (t < nHere) ? hist[t] : 0;
    int pdeg = (deg + 7) & ~7;
    if (t < nHere) dinv[nodeLo + t] = (deg > 0) ? rsqrtf((float)deg) : 0.0f;
    ltmp[t] = pdeg;
    __syncthreads();
    for (int off = 1; off < 256; off <<= 1) {
        int add = (t >= off) ? ltmp[t - off] : 0;
        __syncthreads();
        ltmp[t] += add;
        __syncthreads();
    }
    int lstart = ltmp[t] - pdeg;
    if (t < nHere) rowinfo[nodeLo + t] = make_int2(pb + lstart, pdeg);
    lcur[t] = lstart;
    __syncthreads();
    for (int e = e0 + t; e < e1; e += 256) {
        int2 sd = binned[e];
        int dl = sd.y - nodeLo;
        int pos = atomicAdd(&lcur[dl], 1);
        unsigned int dd = (unsigned int)min(hist[dl], 32767);
        csr[pb + pos] = (unsigned int)sd.x | (dd << 17);
    }
    __syncthreads();
    if (t < nHere && pdeg > deg) {
        unsigned int fill = (deg > 0) ? (csr[pb + lstart] & SRCMASK) : 0u;  // qw=0 dummy
        for (int i = deg; i < pdeg; i++) csr[pb + lstart + i] = fill;
    }
}

// ---------------- finalize weights: |w| = dinv[s]*rsqrt(deg_d), 15-bit fixed-point ----------------
__global__ void k_weights(unsigned int* __restrict__ csr, const float* __restrict__ dinv, int PE) {
    int e = blockIdx.x * blockDim.x + threadIdx.x;
    if (e < PE) {
        unsigned int v = csr[e];
        unsigned int d = v >> 17;
        if (d == 0) return;                       // padding dummy: keep qw=0
        unsigned int s = v & SRCMASK;
        float aw = dinv[s] * rsqrtf((float)d);    // in [0,1]
        unsigned int qw = (unsigned int)(aw * QW_SCALE + 0.5f);
        csr[e] = s | (qw << 17);
    }
}

// ---------------- propagation: y = [2*]prop(gnorm(h)) [- tnorm(tx0)] ----------------
// Wave = 8 dst nodes; 8-lane group per node; lane owns 8 fixed channels (16B).
// Rows padded to x8: pure unroll-8 body, 2 uint4 csr loads + 8 uint4 gathers,
// no tail. 8 outstanding gathers/lane (latency x outstanding model).
__global__ __launch_bounds__(256) void k_prop(const __half* __restrict__ h,
                                              const int2* __restrict__ rowinfo,
                                              const unsigned int* __restrict__ csr,
                                              const __half* __restrict__ tx0,
                                              __half* __restrict__ y, int N,
                                              const float* __restrict__ gstats,
                                              const float* __restrict__ tstats) {
    int lane = threadIdx.x & 63;
    int wv = (blockIdx.x * 256 + threadIdx.x) >> 6;
    int g = lane >> 3, li = lane & 7;
    int node = wv * 8 + g;
    int e = 0, e1 = 0;
    if (node < N) {
        int2 info = rowinfo[node];
        e = info.x;
        e1 = info.x + info.y;
    }
    float acc[8] = {0.f, 0.f, 0.f, 0.f, 0.f, 0.f, 0.f, 0.f};
    float sw = 0.0f;
    const __half* hb = h + li * 8;
    for (; e < e1; e += 8) {
        uint4 c0 = *(const uint4*)(csr + e);
        uint4 c1 = *(const uint4*)(csr + e + 4);
        uint4 a0 = *(const uint4*)(hb + (size_t)(c0.x & SRCMASK) * NCH);
        uint4 a1 = *(const uint4*)(hb + (size_t)(c0.y & SRCMASK) * NCH);
        uint4 a2 = *(const uint4*)(hb + (size_t)(c0.z & SRCMASK) * NCH);
        uint4 a3 = *(const uint4*)(hb + (size_t)(c0.w & SRCMASK) * NCH);
        uint4 a4 = *(const uint4*)(hb + (size_t)(c1.x & SRCMASK) * NCH);
        uint4 a5 = *(const uint4*)(hb + (size_t)(c1.y & SRCMASK) * NCH);
        uint4 a6 = *(const uint4*)(hb + (size_t)(c1.z & SRCMASK) * NCH);
        uint4 a7 = *(const uint4*)(hb + (size_t)(c1.w & SRCMASK) * NCH);
        float w0 = -(float)(c0.x >> 17) * QW_INV;
        float w1 = -(float)(c0.y >> 17) * QW_INV;
        float w2 = -(float)(c0.z >> 17) * QW_INV;
        float w3 = -(float)(c0.w >> 17) * QW_INV;
        float w4 = -(float)(c1.x >> 17) * QW_INV;
        float w5 = -(float)(c1.y >> 17) * QW_INV;
        float w6 = -(float)(c1.z >> 17) * QW_INV;
        float w7 = -(float)(c1.w >> 17) * QW_INV;
        sw += ((w0 + w1) + (w2 + w3)) + ((w4 + w5) + (w6 + w7));
        float2 f;
        f = __half22float2(*(__half2*)&a0.x); acc[0] = fmaf(w0, f.x, acc[0]); acc[1] = fmaf(w0, f.y, acc[1]);
        f = __half22float2(*(__half2*)&a0.y); acc[2] = fmaf(w0, f.x, acc[2]); acc[3] = fmaf(w0, f.y, acc[3]);
        f = __half22float2(*(__half2*)&a0.z); acc[4] = fmaf(w0, f.x, acc[4]); acc[5] = fmaf(w0, f.y, acc[5]);
        f = __half22float2(*(__half2*)&a0.w); acc[6] = fmaf(w0, f.x, acc[6]); acc[7] = fmaf(w0, f.y, acc[7]);
        f = __half22float2(*(__half2*)&a1.x); acc[0] = fmaf(w1, f.x, acc[0]); acc[1] = fmaf(w1, f.y, acc[1]);
        f = __half22float2(*(__half2*)&a1.y); acc[2] = fmaf(w1, f.x, acc[2]); acc[3] = fmaf(w1, f.y, acc[3]);
        f = __half22float2(*(__half2*)&a1.z); acc[4] = fmaf(w1, f.x, acc[4]); acc[5] = fmaf(w1, f.y, acc[5]);
        f = __half22float2(*(__half2*)&a1.w); acc[6] = fmaf(w1, f.x, acc[6]); acc[7] = fmaf(w1, f.y, acc[7]);
        f = __half22float2(*(__half2*)&a2.x); acc[0] = fmaf(w2, f.x, acc[0]); acc[1] = fmaf(w2, f.y, acc[1]);
        f = __half22float2(*(__half2*)&a2.y); acc[2] = fmaf(w2, f.x, acc[2]); acc[3] = fmaf(w2, f.y, acc[3]);
        f = __half22float2(*(__half2*)&a2.z); acc[4] = fmaf(w2, f.x, acc[4]); acc[5] = fmaf(w2, f.y, acc[5]);
        f = __half22float2(*(__half2*)&a2.w); acc[6] = fmaf(w2, f.x, acc[6]); acc[7] = fmaf(w2, f.y, acc[7]);
        f = __half22float2(*(__half2*)&a3.x); acc[0] = fmaf(w3, f.x, acc[0]); acc[1] = fmaf(w3, f.y, acc[1]);
        f = __half22float2(*(__half2*)&a3.y); acc[2] = fmaf(w3, f.x, acc[2]); acc[3] = fmaf(w3, f.y, acc[3]);
        f = __half22float2(*(__half2*)&a3.z); acc[4] = fmaf(w3, f.x, acc[4]); acc[5] = fmaf(w3, f.y, acc[5]);
        f = __half22float2(*(__half2*)&a3.w); acc[6] = fmaf(w3, f.x, acc[6]); acc[7] = fmaf(w3, f.y, acc[7]);
        f = __half22float2(*(__half2*)&a4.x); acc[0] = fmaf(w4, f.x, acc[0]); acc[1] = fmaf(w4, f.y, acc[1]);
        f = __half22float2(*(__half2*)&a4.y); acc[2] = fmaf(w4, f.x, acc[2]); acc[3] = fmaf(w4, f.y, acc[3]);
        f = __half22float2(*(__half2*)&a4.z); acc[4] = fmaf(w4, f.x, acc[4]); acc[5] = fmaf(w4, f.y, acc[5]);
        f = __half22float2(*(__half2*)&a4.w); acc[6] = fmaf(w4, f.x, acc[6]); acc[7] = fmaf(w4, f.y, acc[7]);
        f = __half22float2(*(__half2*)&a5.x); acc[0] = fmaf(w5, f.x, acc[0]); acc[1] = fmaf(w5, f.y, acc[1]);
        f = __half22float2(*(__half2*)&a5.y); acc[2] = fmaf(w5, f.x, acc[2]); acc[3] = fmaf(w5, f.y, acc[3]);
        f = __half22float2(*(__half2*)&a5.z); acc[4] = fmaf(w5, f.x, acc[4]); acc[5] = fmaf(w5, f.y, acc[5]);
        f = __half22float2(*(__half2*)&a5.w); acc[6] = fmaf(w5, f.x, acc[6]); acc[7] = fmaf(w5, f.y, acc[7]);
        f = __half22float2(*(__half2*)&a6.x); acc[0] = fmaf(w6, f.x, acc[0]); acc[1] = fmaf(w6, f.y, acc[1]);
        f = __half22float2(*(__half2*)&a6.y); acc[2] = fmaf(w6, f.x, acc[2]); acc[3] = fmaf(w6, f.y, acc[3]);
        f = __half22float2(*(__half2*)&a6.z); acc[4] = fmaf(w6, f.x, acc[4]); acc[5] = fmaf(w6, f.y, acc[5]);
        f = __half22float2(*(__half2*)&a6.w); acc[6] = fmaf(w6, f.x, acc[6]); acc[7] = fmaf(w6, f.y, acc[7]);
        f = __half22float2(*(__half2*)&a7.x); acc[0] = fmaf(w7, f.x, acc[0]); acc[1] = fmaf(w7, f.y, acc[1]);
        f = __half22float2(*(__half2*)&a7.y); acc[2] = fmaf(w7, f.x, acc[2]); acc[3] = fmaf(w7, f.y, acc[3]);
        f = __half22float2(*(__half2*)&a7.z); acc[4] = fmaf(w7, f.x, acc[4]); acc[5] = fmaf(w7, f.y, acc[5]);
        f = __half22float2(*(__half2*)&a7.w); acc[6] = fmaf(w7, f.x, acc[6]); acc[7] = fmaf(w7, f.y, acc[7]);
    }
    if (node >= N) return;
    if (gstats != nullptr) {
        float4 m0 = *(const float4*)(gstats + li * 8);
        float4 m1 = *(const float4*)(gstats + li * 8 + 4);
        float4 r0 = *(const float4*)(gstats + 64 + li * 8);
        float4 r1 = *(const float4*)(gstats + 64 + li * 8 + 4);
        acc[0] = r0.x * (acc[0] - m0.x * sw);
        acc[1] = r0.y * (acc[1] - m0.y * sw);
        acc[2] = r0.z * (acc[2] - m0.z * sw);
        acc[3] = r0.w * (acc[3] - m0.w * sw);
        acc[4] = r1.x * (acc[4] - m1.x * sw);
        acc[5] = r1.y * (acc[5] - m1.y * sw);
        acc[6] = r1.z * (acc[6] - m1.z * sw);
        acc[7] = r1.w * (acc[7] - m1.w * sw);
    }
    if (tx0 != nullptr) {
        uint4 tq = *(const uint4*)(tx0 + (size_t)node * NCH + li * 8);
        float tv[8];
        float2 f;
        f = __half22float2(*(__half2*)&tq.x); tv[0] = f.x; tv[1] = f.y;
        f = __half22float2(*(__half2*)&tq.y); tv[2] = f.x; tv[3] = f.y;
        f = __half22float2(*(__half2*)&tq.z); tv[4] = f.x; tv[5] = f.y;
        f = __half22float2(*(__half2*)&tq.w); tv[6] = f.x; tv[7] = f.y;
        if (tstats != nullptr) {
            float4 m0 = *(const float4*)(tstats + li * 8);
            float4 m1 = *(const float4*)(tstats + li * 8 + 4);
            float4 r0 = *(const float4*)(tstats + 64 + li * 8);
            float4 r1 = *(const float4*)(tstats + 64 + li * 8 + 4);
            tv[0] = (tv[0] - m0.x) * r0.x; tv[1] = (tv[1] - m0.y) * r0.y;
            tv[2] = (tv[2] - m0.z) * r0.z; tv[3] = (tv[3] - m0.w) * r0.w;
            tv[4] = (tv[4] - m1.x) * r1.x; tv[5] = (tv[5] - m1.y) * r1.y;
            tv[6] = (tv[6] - m1.z) * r1.z; tv[7] = (tv[7] - m1.w) * r1.w;
        }
#pragma unroll
        for (int j = 0; j < 8; j++) acc[j] = 2.0f * acc[j] - tv[j];
    }
    uint4 o;
    __half2 hh;
    hh = __floats2half2_rn(acc[0], acc[1]); o.x = *(unsigned int*)&hh;
    hh = __floats2half2_rn(acc[2], acc[3]); o.y = *(unsigned int*)&hh;
    hh = __floats2half2_rn(acc[4], acc[5]); o.z = *(unsigned int*)&hh;
    hh = __floats2half2_rn(acc[6], acc[7]); o.w = *(unsigned int*)&hh;
    *(uint4*)(y + (size_t)node * NCH + li * 8) = o;
}

// ---------------- MFMA dense combine + bias + ReLU + banked instance-norm stats ----------------
template <typename TOUT>
__global__ __launch_bounds__(256) void k_dmm(const __half* __restrict__ tx0,
                                             const __half* __restrict__ tx1,
                                             const __half* __restrict__ tx2,
                                             const _Float16* __restrict__ Wb,
                                             const float* __restrict__ b,
                                             TOUT* __restrict__ out,
                                             float* __restrict__ statsP, int N,
                                             const float* __restrict__ tstats) {
    __shared__ float sred[64];
    __shared__ float sq[64];
    int t = threadIdx.x;
    int w = t >> 6;
    int lane = t & 63;
    if (t < 64) { sred[t] = 0.f; sq[t] = 0.f; }
    __syncthreads();

    int nb16 = blockIdx.x * 64 + w * 16;
    int m = lane & 15, q = lane >> 4;
    int row = nb16 + m;
    int rowC = (row < N) ? row : 0;
    const __half* base0 = tx0 + (size_t)rowC * NCH;
    const __half* base1 = tx1 + (size_t)rowC * NCH;
    const __half* base2 = tx2 + (size_t)rowC * NCH;

    f32x4 acc[4];
#pragma unroll
    for (int tile = 0; tile < 4; tile++) acc[tile] = (f32x4){0.f, 0.f, 0.f, 0.f};

#pragma unroll
    for (int kk = 0; kk < 6; kk++) {
        const __half* ap = (kk < 2 ? base0 : (kk < 4 ? base1 : base2)) + (kk & 1) * 32 + q * 8;
        f16x8 a = *(const f16x8*)ap;
        if (kk < 2 && tstats != nullptr) {
            int cbase = (kk & 1) * 32 + q * 8;
#pragma unroll
            for (int j = 0; j < 8; j++) {
                float v = (float)a[j];
                a[j] = (_Float16)((v - tstats[cbase + j]) * tstats[64 + cbase + j]);
            }
        }
#pragma unroll
        for (int tile = 0; tile < 4; tile++) {
            f16x8 bf = *(const f16x8*)(Wb + ((size_t)(tile * 6 + kk) * 64 + lane) * 8);
            acc[tile] = __builtin_amdgcn_mfma_f32_16x16x32_f16(a, bf, acc[tile], 0, 0, 0);
        }
    }

#pragma unroll
    for (int tile = 0; tile < 4; tile++) {
        int ch = tile * 16 + m;
        float bb = b[ch];
        float s = 0.f, qq = 0.f;
#pragma unroll
        for (int r = 0; r < 4; r++) {
            int node = nb16 + q * 4 + r;
            float v = fmaxf(acc[tile][r] + bb, 0.f);
            if (node < N) {
                out[(size_t)node * NCH + ch] = (TOUT)v;
                s += v;
                qq = fmaf(v, v, qq);
            }
        }
        s += __shfl_xor(s, 16, 64);  s += __shfl_xor(s, 32, 64);
        qq += __shfl_xor(qq, 16, 64); qq += __shfl_xor(qq, 32, 64);
        if (q == 0) { atomicAdd(&sred[ch], s); atomicAdd(&sq[ch], qq); }
    }
    __syncthreads();
    if (t < 64) {
        int bank = blockIdx.x & (SBANKS - 1);
        atomicAdd(&statsP[bank * 128 + t], sred[t]);
        atomicAdd(&statsP[bank * 128 + 64 + t], sq[t]);
    }
}

__global__ void k_final(float* __restrict__ statsP, float invN) {
    int c = threadIdx.x;  // 64
    float S = 0.f, Q = 0.f;
    for (int k = 0; k < SBANKS; k++) {
        S += statsP[k * 128 + c];
        Q += statsP[k * 128 + 64 + c];
    }
    float m = S * invN;
    float var = Q * invN - m * m;
    statsP[SBANKS * 128 + c] = m;
    statsP[SBANKS * 128 + 64 + c] = rsqrtf(var + EPS);
}

// normalize fp16 A -> fp32 out
__global__ void k_norm_hf(const __half* __restrict__ a, float* __restrict__ o,
                          const float* __restrict__ statsP, int total) {
    int i = blockIdx.x * blockDim.x + threadIdx.x;
    if (i >= total) return;
    int lane = i & 63;
    o[i] = (__half2float(a[i]) - statsP[SBANKS * 128 + lane]) * statsP[SBANKS * 128 + 64 + lane];
}

// ---------------- launcher ----------------
extern "C" void kernel_launch(void* const* d_in, const int* in_sizes, int n_in,
                              void* d_out, int out_size, void* d_ws, size_t ws_size,
                              hipStream_t stream) {
    const float* x  = (const float*)d_in[0];
    const int*   ei = (const int*)d_in[1];
    const float* W1 = (const float*)d_in[2];
    const float* b1 = (const float*)d_in[3];
    const float* W2 = (const float*)d_in[4];
    const float* b2 = (const float*)d_in[5];
    float* out = (float*)d_out;

    const int N = in_sizes[0] / NCH;
    const int E = in_sizes[1] / 2;
    const int* src = ei;
    const int* dst = ei + E;
    const int nbuck = (N + 255) >> BSHIFT;
    const int PE = E + nbuck * PADRES + 8;     // padded csr extent

    // workspace carve (256B aligned)
    char* p = (char*)d_ws;
    auto alloc = [&](size_t bytes) {
        void* r = (void*)p;
        p += ((bytes + 255) / 256) * 256;
        return r;
    };
    float*  dinv     = (float*)alloc((size_t)131072 * 4);  // padded: k_weights may read OOB-src from slack
    int2*   rowinfo  = (int2*)alloc((size_t)N * 8);
    unsigned int* csr = (unsigned int*)alloc((size_t)PE * 4);
    __half* xh       = (__half*)alloc((size_t)N * NCH * 2);
    __half* Tx1      = (__half*)alloc((size_t)N * NCH * 2);
    __half* Tx2      = (__half*)alloc((size_t)N * NCH * 2);
    __half* A        = (__half*)alloc((size_t)N * NCH * 2);
    __half* A2       = (__half*)alloc((size_t)N * NCH * 2);
    _Float16* Wb1    = (_Float16*)alloc(12288 * 2);
    _Float16* Wb2    = (_Float16*)alloc(12288 * 2);
    int*    gbase    = (int*)alloc((size_t)(nbuck + 1) * 4);
    int*    gcur     = (int*)alloc((size_t)nbuck * 4);
    const int statsFloats = SBANKS * 128 + 128;
    // cnt and stats adjacent -> single memset
    int*    cnt      = (int*)alloc((size_t)nbuck * 4 + (size_t)2 * statsFloats * 4);
    float*  stats1   = (float*)(cnt + nbuck);
    float*  stats2   = stats1 + statsFloats;
    const float* nrm1 = stats1 + SBANKS * 128;  // m[64], r[64] after k_final

    // binned aliases Tx1 (dead before first k_prop writes Tx1)
    int2* binned = (int2*)Tx1;

    hipMemsetAsync(cnt, 0, (size_t)nbuck * 4 + (size_t)2 * statsFloats * 4, stream);

    const int TB = 256;
    int nbin = (E + BINCAP - 1) / BINCAP;
    if (nbin < 256) nbin = 256;
    const int perBin = (E + nbin - 1) / nbin;
    const int perH = (E + NHIST - 1) / NHIST;
    const int castTotal = N * NCH;
    const int castB = (castTotal / 4 + TB - 1) / TB;
    k_front<<<castB + 96 + NHIST, TB, 0, stream>>>(x, xh, castTotal, castB,
                                                   W1, Wb1, W2, Wb2,
                                                   dst, cnt, E, perH, nbuck);
    k_bscan<<<1, 512, 0, stream>>>(cnt, gbase, gcur, nbuck, E);
    k_bin<<<nbin, TB, 0, stream>>>(src, dst, gcur, binned, E, perBin, nbuck);
    k_bucket<<<nbuck, TB, 0, stream>>>(binned, gbase, dinv, rowinfo, csr, N, nbuck);
    k_weights<<<(PE + TB - 1) / TB, TB, 0, stream>>>(csr, dinv, PE);

    const int propWaves = (N + 7) / 8;
    const int propBlocks = (propWaves + 3) / 4;
    const int dmmBlocks = (N + 63) / 64;
    const int normBlocks = (N * NCH + TB - 1) / TB;
    const float invN = 1.0f / (float)N;

    // ---- layer 1 (raw x) ----
    k_prop<<<propBlocks, TB, 0, stream>>>(xh, rowinfo, csr, nullptr, Tx1, N, nullptr, nullptr);
    k_prop<<<propBlocks, TB, 0, stream>>>(Tx1, rowinfo, csr, xh, Tx2, N, nullptr, nullptr);
    k_dmm<__half><<<dmmBlocks, TB, 0, stream>>>(xh, Tx1, Tx2, Wb1, b1, A, stats1, N, nullptr);
    k_final<<<1, 64, 0, stream>>>(stats1, invN);

    // ---- layer 2 (A normalized on the fly via nrm1) ----
    k_prop<<<propBlocks, TB, 0, stream>>>(A, rowinfo, csr, nullptr, Tx1, N, nrm1, nullptr);
    k_prop<<<propBlocks, TB, 0, stream>>>(Tx1, rowinfo, csr, A, Tx2, N, nullptr, nrm1);
    k_dmm<__half><<<dmmBlocks, TB, 0, stream>>>(A, Tx1, Tx2, Wb2, b2, A2, stats2, N, nrm1);
    k_final<<<1, 64, 0, stream>>>(stats2, invN);
    k_norm_hf<<<normBlocks, TB, 0, stream>>>(A2, out, stats2, N * NCH);
}

// Round 12
// 329.845 us; speedup vs baseline: 1.0987x; 1.0111x over previous
//
#include <hip/hip_runtime.h>
#include <hip/hip_fp16.h>

#define NCH 64
#define EPS 1e-5f
#define SBANKS 32   // stats atomic banks
#define BSHIFT 8    // 256 dst nodes per bucket
#define NHIST 256   // blocks in hist pass
#define BINCAP 6400 // max edges per k_bin block (LDS capacity)
#define PADRES 2048 // per-bucket csr slack for 8-padding (256*7 + align < 2048)
#define RSHIFT 14   // src-range windows of 16384 rows (2MB) for L2 locality
#define SRCMASK 0x1FFFFu
#define QW_SCALE 32767.0f
#define QW_INV (1.0f/32767.0f)

typedef _Float16 f16x8 __attribute__((ext_vector_type(8)));
typedef float f32x4 __attribute__((ext_vector_type(4)));

// ---------------- fused front: x cast + W1/W2 pack + bucket histogram ----------------
__global__ __launch_bounds__(256) void k_front(const float* __restrict__ x, __half* __restrict__ xh,
                                               int castTotal, int castB,
                                               const float* __restrict__ W1, _Float16* __restrict__ Wb1,
                                               const float* __restrict__ W2, _Float16* __restrict__ Wb2,
                                               const int* __restrict__ dst, int* __restrict__ cnt,
                                               int E, int per, int nbuck) {
    int bid = blockIdx.x;
    if (bid < castB) {
        int i = (bid * 256 + threadIdx.x) * 4;
        if (i < castTotal) {
            float4 f = *(const float4*)(x + i);
            __half2* o = (__half2*)(xh + i);
            o[0] = __floats2half2_rn(f.x, f.y);
            o[1] = __floats2half2_rn(f.z, f.w);
        }
        return;
    }
    if (bid < castB + 96) {
        // W pack: Wb[((tile*6+kk)*64+lane)*8+j] = W[kk*32+(lane>>4)*8+j][tile*16+(lane&15)]
        int wb = bid - castB;
        const float* W = (wb < 48) ? W1 : W2;
        _Float16* Wb = (wb < 48) ? Wb1 : Wb2;
        int idx = (wb % 48) * 256 + threadIdx.x;   // 0..12287
        int j = idx & 7;
        int lane = (idx >> 3) & 63;
        int tk = idx >> 9;
        int tile = tk / 6, kk = tk % 6;
        int k = kk * 32 + (lane >> 4) * 8 + j;
        int n = tile * 16 + (lane & 15);
        Wb[idx] = (_Float16)W[k * 64 + n];
        return;
    }
    // histogram role
    __shared__ int lh[512];
    int hb = bid - castB - 96;
    for (int t = threadIdx.x; t < nbuck; t += 256) lh[t] = 0;
    __syncthreads();
    int lo = hb * per, hi = min(E, lo + per);
    for (int e = lo + threadIdx.x; e < hi; e += 256)
        atomicAdd(&lh[dst[e] >> BSHIFT], 1);
    __syncthreads();
    for (int t = threadIdx.x; t < nbuck; t += 256)
        if (lh[t]) atomicAdd(&cnt[t], lh[t]);
}

// ---------------- scan bucket counts -> base & cursor ----------------
__global__ void k_bscan(const int* __restrict__ cnt, int* __restrict__ gbase,
                        int* __restrict__ gcur, int nbuck, int E) {
    __shared__ int s[512];
    int t = threadIdx.x;
    int v = (t < nbuck) ? cnt[t] : 0;
    s[t] = v;
    __syncthreads();
    for (int off = 1; off < 512; off <<= 1) {
        int add = (t >= off) ? s[t - off] : 0;
        __syncthreads();
        s[t] += add;
        __syncthreads();
    }
    if (t < nbuck) { int ex = s[t] - v; gbase[t] = ex; gcur[t] = ex; }
    if (t == 0) gbase[nbuck] = E;
}

// ---------------- bin edges into bucket segments (LDS counting sort) ----------------
__global__ __launch_bounds__(256) void k_bin(const int* __restrict__ src,
                                             const int* __restrict__ dst,
                                             int* __restrict__ gcur,
                                             int2* __restrict__ binned, int E, int per, int nbuck) {
    __shared__ int lh[512];     // per-block bucket counts
    __shared__ int lsc[512];    // exclusive scan (local run starts)
    __shared__ int lbase[512];  // reserved global run bases
    __shared__ int lcur[512];   // scatter cursors
    __shared__ int2 sedge[BINCAP];
    int t = threadIdx.x;
    for (int i = t; i < 512; i += 256) lh[i] = 0;
    __syncthreads();
    int lo = blockIdx.x * per, hi = min(E, lo + per);
    for (int e = lo + t; e < hi; e += 256)
        atomicAdd(&lh[dst[e] >> BSHIFT], 1);
    __syncthreads();
    int v0 = lh[t], v1 = lh[t + 256];
    lsc[t] = v0; lsc[t + 256] = v1;
    __syncthreads();
    for (int off = 1; off < 512; off <<= 1) {
        int a0 = (t >= off) ? lsc[t - off] : 0;
        int a1 = (t + 256 >= off) ? lsc[t + 256 - off] : 0;
        __syncthreads();
        lsc[t] += a0; lsc[t + 256] += a1;
        __syncthreads();
    }
    lsc[t] -= v0; lsc[t + 256] -= v1;
    if (t < nbuck && v0) lbase[t] = atomicAdd(&gcur[t], v0);
    if (t + 256 < nbuck && v1) lbase[t + 256] = atomicAdd(&gcur[t + 256], v1);
    lcur[t] = lsc[t]; lcur[t + 256] = lsc[t + 256];
    __syncthreads();
    for (int e = lo + t; e < hi; e += 256) {
        int d = dst[e];
        int b = d >> BSHIFT;
        int pos = atomicAdd(&lcur[b], 1);
        sedge[pos] = make_int2(src[e], d);
    }
    __syncthreads();
    int cntE = hi - lo;
    for (int i = t; i < cntE; i += 256) {
        int2 sd = sedge[i];
        int b = sd.y >> BSHIFT;
        binned[lbase[b] + (i - lsc[b])] = sd;
    }
}

// ---------------- per-bucket CSR build, rows padded to x8, src-range ordered ----------------
// rowinfo[node] = {csr start (8-aligned), padded deg}. Within each row, edges are
// grouped by src>>RSHIFT (8 ascending 2MB windows) so concurrently-running prop
// waves gather within an L2-resident window. Padding slots: row's first src, qw=0.
__global__ __launch_bounds__(256) void k_bucket(const int2* __restrict__ binned,
                                                const int* __restrict__ gbase,
                                                float* __restrict__ dinv,
                                                int2* __restrict__ rowinfo,
                                                unsigned int* __restrict__ csr, int N, int nbuck) {
    __shared__ int hist8[256 * 8];   // (node, src-range) counts
    __shared__ int cur8[256 * 8];    // scatter cursors
    __shared__ int ldeg[256];
    __shared__ int ltmp[256];
    int b = blockIdx.x;
    int t = threadIdx.x;
    int nodeLo = b << BSHIFT;
    int nHere = min(256, N - nodeLo);
    int e0 = gbase[b], e1 = gbase[b + 1];
    int pb = (gbase[b] + b * PADRES + 7) & ~7;   // 8-aligned padded base
    for (int i = t; i < 256 * 8; i += 256) hist8[i] = 0;
    __syncthreads();
    for (int e = e0 + t; e < e1; e += 256) {
        int2 sd = binned[e];
        atomicAdd(&hist8[((sd.y - nodeLo) << 3) + (sd.x >> RSHIFT)], 1);
    }
    __syncthreads();
    int c[8], deg = 0;
#pragma unroll
    for (int r = 0; r < 8; r++) { c[r] = hist8[(t << 3) + r]; deg += c[r]; }
    int pdeg = (deg + 7) & ~7;
    ldeg[t] = deg;
    if (t < nHere) dinv[nodeLo + t] = (deg > 0) ? rsqrtf((float)deg) : 0.0f;
    ltmp[t] = pdeg;
    __syncthreads();
    for (int off = 1; off < 256; off <<= 1) {
        int add = (t >= off) ? ltmp[t - off] : 0;
        __syncthreads();
        ltmp[t] += add;
        __syncthreads();
    }
    int lstart = ltmp[t] - pdeg;
    if (t < nHere) rowinfo[nodeLo + t] = make_int2(pb + lstart, pdeg);
    // within-row range starts
    int run = lstart;
#pragma unroll
    for (int r = 0; r < 8; r++) { cur8[(t << 3) + r] = run; run += c[r]; }
    __syncthreads();
    for (int e = e0 + t; e < e1; e += 256) {
        int2 sd = binned[e];
        int dl = sd.y - nodeLo;
        int pos = atomicAdd(&cur8[(dl << 3) + (sd.x >> RSHIFT)], 1);
        unsigned int dd = (unsigned int)min(ldeg[dl], 32767);
        csr[pb + pos] = (unsigned int)sd.x | (dd << 17);
    }
    __syncthreads();
    if (t < nHere) {
        int d = ldeg[t];
        int pd = (d + 7) & ~7;
        if (pd > d) {
            unsigned int fill = (d > 0) ? (csr[pb + lstart] & SRCMASK) : 0u;  // qw=0 dummy
            for (int i = d; i < pd; i++) csr[pb + lstart + i] = fill;
        }
    }
}

// ---------------- finalize weights: |w| = dinv[s]*rsqrt(deg_d), 15-bit fixed-point ----------------
__global__ void k_weights(unsigned int* __restrict__ csr, const float* __restrict__ dinv, int PE) {
    int e = blockIdx.x * blockDim.x + threadIdx.x;
    if (e < PE) {
        unsigned int v = csr[e];
        unsigned int d = v >> 17;
        if (d == 0) return;                       // padding dummy: keep qw=0
        unsigned int s = v & SRCMASK;
        float aw = dinv[s] * rsqrtf((float)d);    // in [0,1]
        unsigned int qw = (unsigned int)(aw * QW_SCALE + 0.5f);
        csr[e] = s | (qw << 17);
    }
}

// ---------------- propagation: y = [2*]prop(gnorm(h)) [- tnorm(tx0)] ----------------
// Wave = 8 dst nodes; 8-lane group per node; lane owns 8 fixed channels (16B).
// Rows padded to x8 and src-range-ordered: pure unroll-8 body, no tail.
__global__ __launch_bounds__(256) void k_prop(const __half* __restrict__ h,
                                              const int2* __restrict__ rowinfo,
                                              const unsigned int* __restrict__ csr,
                                              const __half* __restrict__ tx0,
                                              __half* __restrict__ y, int N,
                                              const float* __restrict__ gstats,
                                              const float* __restrict__ tstats) {
    int lane = threadIdx.x & 63;
    int wv = (blockIdx.x * 256 + threadIdx.x) >> 6;
    int g = lane >> 3, li = lane & 7;
    int node = wv * 8 + g;
    int e = 0, e1 = 0;
    if (node < N) {
        int2 info = rowinfo[node];
        e = info.x;
        e1 = info.x + info.y;
    }
    float acc[8] = {0.f, 0.f, 0.f, 0.f, 0.f, 0.f, 0.f, 0.f};
    float sw = 0.0f;
    const __half* hb = h + li * 8;
    for (; e < e1; e += 8) {
        uint4 c0 = *(const uint4*)(csr + e);
        uint4 c1 = *(const uint4*)(csr + e + 4);
        uint4 a0 = *(const uint4*)(hb + (size_t)(c0.x & SRCMASK) * NCH);
        uint4 a1 = *(const uint4*)(hb + (size_t)(c0.y & SRCMASK) * NCH);
        uint4 a2 = *(const uint4*)(hb + (size_t)(c0.z & SRCMASK) * NCH);
        uint4 a3 = *(const uint4*)(hb + (size_t)(c0.w & SRCMASK) * NCH);
        uint4 a4 = *(const uint4*)(hb + (size_t)(c1.x & SRCMASK) * NCH);
        uint4 a5 = *(const uint4*)(hb + (size_t)(c1.y & SRCMASK) * NCH);
        uint4 a6 = *(const uint4*)(hb + (size_t)(c1.z & SRCMASK) * NCH);
        uint4 a7 = *(const uint4*)(hb + (size_t)(c1.w & SRCMASK) * NCH);
        float w0 = -(float)(c0.x >> 17) * QW_INV;
        float w1 = -(float)(c0.y >> 17) * QW_INV;
        float w2 = -(float)(c0.z >> 17) * QW_INV;
        float w3 = -(float)(c0.w >> 17) * QW_INV;
        float w4 = -(float)(c1.x >> 17) * QW_INV;
        float w5 = -(float)(c1.y >> 17) * QW_INV;
        float w6 = -(float)(c1.z >> 17) * QW_INV;
        float w7 = -(float)(c1.w >> 17) * QW_INV;
        sw += ((w0 + w1) + (w2 + w3)) + ((w4 + w5) + (w6 + w7));
        float2 f;
        f = __half22float2(*(__half2*)&a0.x); acc[0] = fmaf(w0, f.x, acc[0]); acc[1] = fmaf(w0, f.y, acc[1]);
        f = __half22float2(*(__half2*)&a0.y); acc[2] = fmaf(w0, f.x, acc[2]); acc[3] = fmaf(w0, f.y, acc[3]);
        f = __half22float2(*(__half2*)&a0.z); acc[4] = fmaf(w0, f.x, acc[4]); acc[5] = fmaf(w0, f.y, acc[5]);
        f = __half22float2(*(__half2*)&a0.w); acc[6] = fmaf(w0, f.x, acc[6]); acc[7] = fmaf(w0, f.y, acc[7]);
        f = __half22float2(*(__half2*)&a1.x); acc[0] = fmaf(w1, f.x, acc[0]); acc[1] = fmaf(w1, f.y, acc[1]);
        f = __half22float2(*(__half2*)&a1.y); acc[2] = fmaf(w1, f.x, acc[2]); acc[3] = fmaf(w1, f.y, acc[3]);
        f = __half22float2(*(__half2*)&a1.z); acc[4] = fmaf(w1, f.x, acc[4]); acc[5] = fmaf(w1, f.y, acc[5]);
        f = __half22float2(*(__half2*)&a1.w); acc[6] = fmaf(w1, f.x, acc[6]); acc[7] = fmaf(w1, f.y, acc[7]);
        f = __half22float2(*(__half2*)&a2.x); acc[0] = fmaf(w2, f.x, acc[0]); acc[1] = fmaf(w2, f.y, acc[1]);
        f = __half22float2(*(__half2*)&a2.y); acc[2] = fmaf(w2, f.x, acc[2]); acc[3] = fmaf(w2, f.y, acc[3]);
        f = __half22float2(*(__half2*)&a2.z); acc[4] = fmaf(w2, f.x, acc[4]); acc[5] = fmaf(w2, f.y, acc[5]);
        f = __half22float2(*(__half2*)&a2.w); acc[6] = fmaf(w2, f.x, acc[6]); acc[7] = fmaf(w2, f.y, acc[7]);
        f = __half22float2(*(__half2*)&a3.x); acc[0] = fmaf(w3, f.x, acc[0]); acc[1] = fmaf(w3, f.y, acc[1]);
        f = __half22float2(*(__half2*)&a3.y); acc[2] = fmaf(w3, f.x, acc[2]); acc[3] = fmaf(w3, f.y, acc[3]);
        f = __half22float2(*(__half2*)&a3.z); acc[4] = fmaf(w3, f.x, acc[4]); acc[5] = fmaf(w3, f.y, acc[5]);
        f = __half22float2(*(__half2*)&a3.w); acc[6] = fmaf(w3, f.x, acc[6]); acc[7] = fmaf(w3, f.y, acc[7]);
        f = __half22float2(*(__half2*)&a4.x); acc[0] = fmaf(w4, f.x, acc[0]); acc[1] = fmaf(w4, f.y, acc[1]);
        f = __half22float2(*(__half2*)&a4.y); acc[2] = fmaf(w4, f.x, acc[2]); acc[3] = fmaf(w4, f.y, acc[3]);
        f = __half22float2(*(__half2*)&a4.z); acc[4] = fmaf(w4, f.x, acc[4]); acc[5] = fmaf(w4, f.y, acc[5]);
        f = __half22float2(*(__half2*)&a4.w); acc[6] = fmaf(w4, f.x, acc[6]); acc[7] = fmaf(w4, f.y, acc[7]);
        f = __half22float2(*(__half2*)&a5.x); acc[0] = fmaf(w5, f.x, acc[0]); acc[1] = fmaf(w5, f.y, acc[1]);
        f = __half22float2(*(__half2*)&a5.y); acc[2] = fmaf(w5, f.x, acc[2]); acc[3] = fmaf(w5, f.y, acc[3]);
        f = __half22float2(*(__half2*)&a5.z); acc[4] = fmaf(w5, f.x, acc[4]); acc[5] = fmaf(w5, f.y, acc[5]);
        f = __half22float2(*(__half2*)&a5.w); acc[6] = fmaf(w5, f.x, acc[6]); acc[7] = fmaf(w5, f.y, acc[7]);
        f = __half22float2(*(__half2*)&a6.x); acc[0] = fmaf(w6, f.x, acc[0]); acc[1] = fmaf(w6, f.y, acc[1]);
        f = __half22float2(*(__half2*)&a6.y); acc[2] = fmaf(w6, f.x, acc[2]); acc[3] = fmaf(w6, f.y, acc[3]);
        f = __half22float2(*(__half2*)&a6.z); acc[4] = fmaf(w6, f.x, acc[4]); acc[5] = fmaf(w6, f.y, acc[5]);
        f = __half22float2(*(__half2*)&a6.w); acc[6] = fmaf(w6, f.x, acc[6]); acc[7] = fmaf(w6, f.y, acc[7]);
        f = __half22float2(*(__half2*)&a7.x); acc[0] = fmaf(w7, f.x, acc[0]); acc[1] = fmaf(w7, f.y, acc[1]);
        f = __half22float2(*(__half2*)&a7.y); acc[2] = fmaf(w7, f.x, acc[2]); acc[3] = fmaf(w7, f.y, acc[3]);
        f = __half22float2(*(__half2*)&a7.z); acc[4] = fmaf(w7, f.x, acc[4]); acc[5] = fmaf(w7, f.y, acc[5]);
        f = __half22float2(*(__half2*)&a7.w); acc[6] = fmaf(w7, f.x, acc[6]); acc[7] = fmaf(w7, f.y, acc[7]);
    }
    if (node >= N) return;
    if (gstats != nullptr) {
        float4 m0 = *(const float4*)(gstats + li * 8);
        float4 m1 = *(const float4*)(gstats + li * 8 + 4);
        float4 r0 = *(const float4*)(gstats + 64 + li * 8);
        float4 r1 = *(const float4*)(gstats + 64 + li * 8 + 4);
        acc[0] = r0.x * (acc[0] - m0.x * sw);
        acc[1] = r0.y * (acc[1] - m0.y * sw);
        acc[2] = r0.z * (acc[2] - m0.z * sw);
        acc[3] = r0.w * (acc[3] - m0.w * sw);
        acc[4] = r1.x * (acc[4] - m1.x * sw);
        acc[5] = r1.y * (acc[5] - m1.y * sw);
        acc[6] = r1.z * (acc[6] - m1.z * sw);
        acc[7] = r1.w * (acc[7] - m1.w * sw);
    }
    if (tx0 != nullptr) {
        uint4 tq = *(const uint4*)(tx0 + (size_t)node * NCH + li * 8);
        float tv[8];
        float2 f;
        f = __half22float2(*(__half2*)&tq.x); tv[0] = f.x; tv[1] = f.y;
        f = __half22float2(*(__half2*)&tq.y); tv[2] = f.x; tv[3] = f.y;
        f = __half22float2(*(__half2*)&tq.z); tv[4] = f.x; tv[5] = f.y;
        f = __half22float2(*(__half2*)&tq.w); tv[6] = f.x; tv[7] = f.y;
        if (tstats != nullptr) {
            float4 m0 = *(const float4*)(tstats + li * 8);
            float4 m1 = *(const float4*)(tstats + li * 8 + 4);
            float4 r0 = *(const float4*)(tstats + 64 + li * 8);
            float4 r1 = *(const float4*)(tstats + 64 + li * 8 + 4);
            tv[0] = (tv[0] - m0.x) * r0.x; tv[1] = (tv[1] - m0.y) * r0.y;
            tv[2] = (tv[2] - m0.z) * r0.z; tv[3] = (tv[3] - m0.w) * r0.w;
            tv[4] = (tv[4] - m1.x) * r1.x; tv[5] = (tv[5] - m1.y) * r1.y;
            tv[6] = (tv[6] - m1.z) * r1.z; tv[7] = (tv[7] - m1.w) * r1.w;
        }
#pragma unroll
        for (int j = 0; j < 8; j++) acc[j] = 2.0f * acc[j] - tv[j];
    }
    uint4 o;
    __half2 hh;
    hh = __floats2half2_rn(acc[0], acc[1]); o.x = *(unsigned int*)&hh;
    hh = __floats2half2_rn(acc[2], acc[3]); o.y = *(unsigned int*)&hh;
    hh = __floats2half2_rn(acc[4], acc[5]); o.z = *(unsigned int*)&hh;
    hh = __floats2half2_rn(acc[6], acc[7]); o.w = *(unsigned int*)&hh;
    *(uint4*)(y + (size_t)node * NCH + li * 8) = o;
}

// ---------------- MFMA dense combine + bias + ReLU + banked instance-norm stats ----------------
template <typename TOUT>
__global__ __launch_bounds__(256) void k_dmm(const __half* __restrict__ tx0,
                                             const __half* __restrict__ tx1,
                                             const __half* __restrict__ tx2,
                                             const _Float16* __restrict__ Wb,
                                             const float* __restrict__ b,
                                             TOUT* __restrict__ out,
                                             float* __restrict__ statsP, int N,
                                             const float* __restrict__ tstats) {
    __shared__ float sred[64];
    __shared__ float sq[64];
    int t = threadIdx.x;
    int w = t >> 6;
    int lane = t & 63;
    if (t < 64) { sred[t] = 0.f; sq[t] = 0.f; }
    __syncthreads();

    int nb16 = blockIdx.x * 64 + w * 16;
    int m = lane & 15, q = lane >> 4;
    int row = nb16 + m;
    int rowC = (row < N) ? row : 0;
    const __half* base0 = tx0 + (size_t)rowC * NCH;
    const __half* base1 = tx1 + (size_t)rowC * NCH;
    const __half* base2 = tx2 + (size_t)rowC * NCH;

    f32x4 acc[4];
#pragma unroll
    for (int tile = 0; tile < 4; tile++) acc[tile] = (f32x4){0.f, 0.f, 0.f, 0.f};

#pragma unroll
    for (int kk = 0; kk < 6; kk++) {
        const __half* ap = (kk < 2 ? base0 : (kk < 4 ? base1 : base2)) + (kk & 1) * 32 + q * 8;
        f16x8 a = *(const f16x8*)ap;
        if (kk < 2 && tstats != nullptr) {
            int cbase = (kk & 1) * 32 + q * 8;
#pragma unroll
            for (int j = 0; j < 8; j++) {
                float v = (float)a[j];
                a[j] = (_Float16)((v - tstats[cbase + j]) * tstats[64 + cbase + j]);
            }
        }
#pragma unroll
        for (int tile = 0; tile < 4; tile++) {
            f16x8 bf = *(const f16x8*)(Wb + ((size_t)(tile * 6 + kk) * 64 + lane) * 8);
            acc[tile] = __builtin_amdgcn_mfma_f32_16x16x32_f16(a, bf, acc[tile], 0, 0, 0);
        }
    }

#pragma unroll
    for (int tile = 0; tile < 4; tile++) {
        int ch = tile * 16 + m;
        float bb = b[ch];
        float s = 0.f, qq = 0.f;
#pragma unroll
        for (int r = 0; r < 4; r++) {
            int node = nb16 + q * 4 + r;
            float v = fmaxf(acc[tile][r] + bb, 0.f);
            if (node < N) {
                out[(size_t)node * NCH + ch] = (TOUT)v;
                s += v;
                qq = fmaf(v, v, qq);
            }
        }
        s += __shfl_xor(s, 16, 64);  s += __shfl_xor(s, 32, 64);
        qq += __shfl_xor(qq, 16, 64); qq += __shfl_xor(qq, 32, 64);
        if (q == 0) { atomicAdd(&sred[ch], s); atomicAdd(&sq[ch], qq); }
    }
    __syncthreads();
    if (t < 64) {
        int bank = blockIdx.x & (SBANKS - 1);
        atomicAdd(&statsP[bank * 128 + t], sred[t]);
        atomicAdd(&statsP[bank * 128 + 64 + t], sq[t]);
    }
}

__global__ void k_final(float* __restrict__ statsP, float invN) {
    int c = threadIdx.x;  // 64
    float S = 0.f, Q = 0.f;
    for (int k = 0; k < SBANKS; k++) {
        S += statsP[k * 128 + c];
        Q += statsP[k * 128 + 64 + c];
    }
    float m = S * invN;
    float var = Q * invN - m * m;
    statsP[SBANKS * 128 + c] = m;
    statsP[SBANKS * 128 + 64 + c] = rsqrtf(var + EPS);
}

// normalize fp16 A -> fp32 out
__global__ void k_norm_hf(const __half* __restrict__ a, float* __restrict__ o,
                          const float* __restrict__ statsP, int total) {
    int i = blockIdx.x * blockDim.x + threadIdx.x;
    if (i >= total) return;
    int lane = i & 63;
    o[i] = (__half2float(a[i]) - statsP[SBANKS * 128 + lane]) * statsP[SBANKS * 128 + 64 + lane];
}

// ---------------- launcher ----------------
extern "C" void kernel_launch(void* const* d_in, const int* in_sizes, int n_in,
                              void* d_out, int out_size, void* d_ws, size_t ws_size,
                              hipStream_t stream) {
    const float* x  = (const float*)d_in[0];
    const int*   ei = (const int*)d_in[1];
    const float* W1 = (const float*)d_in[2];
    const float* b1 = (const float*)d_in[3];
    const float* W2 = (const float*)d_in[4];
    const float* b2 = (const float*)d_in[5];
    float* out = (float*)d_out;

    const int N = in_sizes[0] / NCH;
    const int E = in_sizes[1] / 2;
    const int* src = ei;
    const int* dst = ei + E;
    const int nbuck = (N + 255) >> BSHIFT;
    const int PE = E + nbuck * PADRES + 8;     // padded csr extent

    // workspace carve (256B aligned)
    char* p = (char*)d_ws;
    auto alloc = [&](size_t bytes) {
        void* r = (void*)p;
        p += ((bytes + 255) / 256) * 256;
        return r;
    };
    float*  dinv     = (float*)alloc((size_t)131072 * 4);  // padded: k_weights may read OOB-src from slack
    int2*   rowinfo  = (int2*)alloc((size_t)N * 8);
    unsigned int* csr = (unsigned int*)alloc((size_t)PE * 4);
    __half* xh       = (__half*)alloc((size_t)N * NCH * 2);
    __half* Tx1      = (__half*)alloc((size_t)N * NCH * 2);
    __half* Tx2      = (__half*)alloc((size_t)N * NCH * 2);
    __half* A        = (__half*)alloc((size_t)N * NCH * 2);
    __half* A2       = (__half*)alloc((size_t)N * NCH * 2);
    _Float16* Wb1    = (_Float16*)alloc(12288 * 2);
    _Float16* Wb2    = (_Float16*)alloc(12288 * 2);
    int*    gbase    = (int*)alloc((size_t)(nbuck + 1) * 4);
    int*    gcur     = (int*)alloc((size_t)nbuck * 4);
    const int statsFloats = SBANKS * 128 + 128;
    // cnt and stats adjacent -> single memset
    int*    cnt      = (int*)alloc((size_t)nbuck * 4 + (size_t)2 * statsFloats * 4);
    float*  stats1   = (float*)(cnt + nbuck);
    float*  stats2   = stats1 + statsFloats;
    const float* nrm1 = stats1 + SBANKS * 128;  // m[64], r[64] after k_final

    // binned aliases Tx1 (dead before first k_prop writes Tx1)
    int2* binned = (int2*)Tx1;

    hipMemsetAsync(cnt, 0, (size_t)nbuck * 4 + (size_t)2 * statsFloats * 4, stream);

    const int TB = 256;
    int nbin = (E + BINCAP - 1) / BINCAP;
    if (nbin < 256) nbin = 256;
    const int perBin = (E + nbin - 1) / nbin;
    const int perH = (E + NHIST - 1) / NHIST;
    const int castTotal = N * NCH;
    const int castB = (castTotal / 4 + TB - 1) / TB;
    k_front<<<castB + 96 + NHIST, TB, 0, stream>>>(x, xh, castTotal, castB,
                                                   W1, Wb1, W2, Wb2,
                                                   dst, cnt, E, perH, nbuck);
    k_bscan<<<1, 512, 0, stream>>>(cnt, gbase, gcur, nbuck, E);
    k_bin<<<nbin, TB, 0, stream>>>(src, dst, gcur, binned, E, perBin, nbuck);
    k_bucket<<<nbuck, TB, 0, stream>>>(binned, gbase, dinv, rowinfo, csr, N, nbuck);
    k_weights<<<(PE + TB - 1) / TB, TB, 0, stream>>>(csr, dinv, PE);

    const int propWaves = (N + 7) / 8;
    const int propBlocks = (propWaves + 3) / 4;
    const int dmmBlocks = (N + 63) / 64;
    const int normBlocks = (N * NCH + TB - 1) / TB;
    const float invN = 1.0f / (float)N;

    // ---- layer 1 (raw x) ----
    k_prop<<<propBlocks, TB, 0, stream>>>(xh, rowinfo, csr, nullptr, Tx1, N, nullptr, nullptr);
    k_prop<<<propBlocks, TB, 0, stream>>>(Tx1, rowinfo, csr, xh, Tx2, N, nullptr, nullptr);
    k_dmm<__half><<<dmmBlocks, TB, 0, stream>>>(xh, Tx1, Tx2, Wb1, b1, A, stats1, N, nullptr);
    k_final<<<1, 64, 0, stream>>>(stats1, invN);

    // ---- layer 2 (A normalized on the fly via nrm1) ----
    k_prop<<<propBlocks, TB, 0, stream>>>(A, rowinfo, csr, nullptr, Tx1, N, nrm1, nullptr);
    k_prop<<<propBlocks, TB, 0, stream>>>(Tx1, rowinfo, csr, A, Tx2, N, nullptr, nrm1);
    k_dmm<__half><<<dmmBlocks, TB, 0, stream>>>(A, Tx1, Tx2, Wb2, b2, A2, stats2, N, nrm1);
    k_final<<<1, 64, 0, stream>>>(stats2, invN);
    k_norm_hf<<<normBlocks, TB, 0, stream>>>(A2, out, stats2, N * NCH);
}